// Round 4
// baseline (720.773 us; speedup 1.0000x reference)
//
#include <hip/hip_runtime.h>

typedef unsigned short u16;
typedef unsigned int u32;
typedef __bf16 bf16x8 __attribute__((ext_vector_type(8)));
typedef float f32x4 __attribute__((ext_vector_type(4)));

__device__ __forceinline__ u16 f2bf(float f) {
    union { float f; u32 u; } v; v.f = f;
    u32 r = v.u + 0x7FFFu + ((v.u >> 16) & 1u);   // RNE
    return (u16)(r >> 16);
}
__device__ __forceinline__ float bf2f(u16 h) {
    union { u32 u; float f; } v; v.u = (u32)h << 16; return v.f;
}

// ---------------------------------------------------------------------------
// bf16 GEMM: C[M,N] = A[M,K] @ Bt[N,K]^T (+bias, optional relu)
// If Cb != null, writes bf16 output there instead of fp32 C.
// 128x128 tile, BK=64, 4 waves, 16x16x32 MFMA, global_load_lds width 16,
// XOR-swizzled LDS (chunk ^= row&7). M%128==0, N%128==0, K%64==0.
// ---------------------------------------------------------------------------
__global__ __launch_bounds__(256) void gemm_bt(
    const u16* __restrict__ A, const u16* __restrict__ Bt,
    float* __restrict__ C, u16* __restrict__ Cb, const float* __restrict__ bias,
    int M, int N, int K, int relu)
{
    __shared__ char lA[128 * 64 * 2];
    __shared__ char lB[128 * 64 * 2];
    const int t = threadIdx.x;
    const int w = t >> 6, l = t & 63;
    const int bn = blockIdx.x, bm = blockIdx.y;
    const int wr = w >> 1, wc = w & 1;

    const int srow = w * 8 + (l >> 3);
    const int scol = ((l & 7) ^ (l >> 3)) << 3;     // pre-swizzled source chunk
    const u16* gA = A + (size_t)(bm * 128 + srow) * K + scol;
    const u16* gB = Bt + (size_t)(bn * 128 + srow) * K + scol;

    f32x4 zero = {0.f, 0.f, 0.f, 0.f};
    f32x4 acc[4][4];
#pragma unroll
    for (int i = 0; i < 4; i++)
#pragma unroll
        for (int j = 0; j < 4; j++) acc[i][j] = zero;

    const int arow = wr * 64 + (l & 15);
    const int brow = wc * 64 + (l & 15);
    const int kx = l >> 4;
    const int sw = l & 7;       // == row&7 for fragment rows

    for (int k0 = 0; k0 < K; k0 += 64) {
#pragma unroll
        for (int c2 = 0; c2 < 4; ++c2) {
            __builtin_amdgcn_global_load_lds(
                (const __attribute__((address_space(1))) void*)(gA + (size_t)c2 * 32 * K + k0),
                (__attribute__((address_space(3))) void*)(lA + c2 * 4096 + w * 1024), 16, 0, 0);
            __builtin_amdgcn_global_load_lds(
                (const __attribute__((address_space(1))) void*)(gB + (size_t)c2 * 32 * K + k0),
                (__attribute__((address_space(3))) void*)(lB + c2 * 4096 + w * 1024), 16, 0, 0);
        }
        __syncthreads();
#pragma unroll
        for (int kk = 0; kk < 2; ++kk) {
            bf16x8 af[4], bfr[4];
#pragma unroll
            for (int mi = 0; mi < 4; ++mi)
                af[mi] = *(const bf16x8*)(lA + (arow + mi * 16) * 128 + (((kk * 4 + kx) ^ sw) << 4));
#pragma unroll
            for (int ni = 0; ni < 4; ++ni)
                bfr[ni] = *(const bf16x8*)(lB + (brow + ni * 16) * 128 + (((kk * 4 + kx) ^ sw) << 4));
#pragma unroll
            for (int mi = 0; mi < 4; ++mi)
#pragma unroll
                for (int ni = 0; ni < 4; ++ni)
                    acc[mi][ni] = __builtin_amdgcn_mfma_f32_16x16x32_bf16(af[mi], bfr[ni], acc[mi][ni], 0, 0, 0);
        }
        __syncthreads();
    }

    const int cm = bm * 128 + wr * 64;
    const int cn = bn * 128 + wc * 64;
#pragma unroll
    for (int mi = 0; mi < 4; ++mi) {
#pragma unroll
        for (int ni = 0; ni < 4; ++ni) {
            int row0 = cm + mi * 16 + (l >> 4) * 4;
            int col = cn + ni * 16 + (l & 15);
            float bv = bias ? bias[col] : 0.f;
#pragma unroll
            for (int r = 0; r < 4; ++r) {
                float v = acc[mi][ni][r] + bv;
                if (relu) v = fmaxf(v, 0.f);
                if (Cb) Cb[(size_t)(row0 + r) * N + col] = f2bf(v);
                else    C [(size_t)(row0 + r) * N + col] = v;
            }
        }
    }
}

// ---------------------------------------------------------------------------
// batched fp32 -> bf16 weight conversion (4 jobs, blockIdx.z selects)
struct CJob { const float* src; u16* dst; long n4; };
struct CJobs4 { CJob j[4]; };
__global__ void conv4_bf16(CJobs4 jobs)
{
    CJob jb = jobs.j[blockIdx.z];
    long i = (long)blockIdx.x * blockDim.x + threadIdx.x;
    long stride = (long)gridDim.x * blockDim.x;
    for (; i < jb.n4; i += stride) {
        float4 v = ((const float4*)jb.src)[i];
        ushort4 o;
        o.x = f2bf(v.x); o.y = f2bf(v.y); o.z = f2bf(v.z); o.w = f2bf(v.w);
        ((ushort4*)jb.dst)[i] = o;
    }
}

// batched transpose fp32 [Rr,Cc] -> bf16 out[c*ldo + r]
struct TJob { const float* src; u16* dst; int Rr, Cc, ldo; };
struct TJobs4 { TJob j[4]; };
__global__ void transpose4_bf16(TJobs4 jobs)
{
    TJob jb = jobs.j[blockIdx.z];
    __shared__ float tile[32][33];
    int c0 = blockIdx.x * 32, r0 = blockIdx.y * 32;
    if (c0 >= jb.Cc || r0 >= jb.Rr) return;
    int tx = threadIdx.x, ty = threadIdx.y;
    for (int dy = 0; dy < 32; dy += 8) {
        int r = r0 + ty + dy, c = c0 + tx;
        tile[ty + dy][tx] = (r < jb.Rr && c < jb.Cc) ? jb.src[(size_t)r * jb.Cc + c] : 0.f;
    }
    __syncthreads();
    for (int dy = 0; dy < 32; dy += 8) {
        int c = c0 + ty + dy, r = r0 + tx;
        if (c < jb.Cc && r < jb.Rr) jb.dst[(size_t)c * jb.ldo + r] = f2bf(tile[tx][ty + dy]);
    }
}

// nodes fp32 [Nn,768] -> bf16 into Abig[Mpad,1536] cols 0:768, pad rows zero
__global__ void conv_nodes_str(const float* __restrict__ nodes, u16* __restrict__ Abig,
                               int Nn, int Mpad)
{
    long i = (long)blockIdx.x * blockDim.x + threadIdx.x;
    long stride = (long)gridDim.x * blockDim.x;
    long n4 = (long)Mpad * 192;     // float4 groups over [Mpad,768]
    for (; i < n4; i += stride) {
        long row = i / 192, c4 = i % 192;
        ushort4 o;
        if ((int)row < Nn) {
            float4 v = ((const float4*)nodes)[i];
            o.x = f2bf(v.x); o.y = f2bf(v.y); o.z = f2bf(v.z); o.w = f2bf(v.w);
        } else { o.x = 0; o.y = 0; o.z = 0; o.w = 0; }
        ((ushort4*)Abig)[row * 384 + c4] = o;
    }
}

__global__ void gather_x0(const float* __restrict__ nodes, const int* __restrict__ opt,
                          float* __restrict__ x0, u16* __restrict__ x0b, int H)
{
    int r = blockIdx.x;
    size_t srcb = (size_t)opt[r] * H;
    for (int c = threadIdx.x; c < H; c += blockDim.x) {
        float v = nodes[srcb + c];
        x0[(size_t)r * H + c] = v;
        x0b[(size_t)r * H + c] = f2bf(v);
    }
}

// x2 fp32 [R,768] -> Abig rows opt[r], cols 0:768 (bf16)
__global__ void scatter_opts_str(const float* __restrict__ x2, const int* __restrict__ opt,
                                 u16* __restrict__ Abig)
{
    int r = blockIdx.x;
    size_t dstb = (size_t)opt[r] * 1536;
    for (int c = threadIdx.x; c < 768; c += blockDim.x)
        Abig[dstb + c] = f2bf(x2[(size_t)r * 768 + c]);
}

// S=4 attention (enc1), bf16 out; one block per (batch,head), wave w = query row
__global__ __launch_bounds__(256) void attn_small_b(
    const float* __restrict__ qkv, u16* __restrict__ out, int H, int nh, int hd)
{
    int b = blockIdx.x / nh, h = blockIdx.x % nh;
    int w = threadIdx.x >> 6, l = threadIdx.x & 63;
    __shared__ float sc[4][4];
    int qs = 3 * H;
    const float* qr = qkv + (size_t)(b * 4 + w) * qs + h * hd;
    float scale = rsqrtf((float)hd);
    for (int sj = 0; sj < 4; ++sj) {
        const float* kr = qkv + (size_t)(b * 4 + sj) * qs + H + h * hd;
        float p = 0.f;
        for (int i = l; i < hd; i += 64) p += qr[i] * kr[i];
        for (int off = 32; off; off >>= 1) p += __shfl_down(p, off, 64);
        if (l == 0) sc[w][sj] = p * scale;
    }
    __syncthreads();
    float a0 = sc[w][0], a1 = sc[w][1], a2 = sc[w][2], a3 = sc[w][3];
    float mx = fmaxf(fmaxf(a0, a1), fmaxf(a2, a3));
    float e0 = __expf(a0 - mx), e1 = __expf(a1 - mx), e2 = __expf(a2 - mx), e3 = __expf(a3 - mx);
    float inv = 1.f / (e0 + e1 + e2 + e3);
    e0 *= inv; e1 *= inv; e2 *= inv; e3 *= inv;
    const float* v0 = qkv + (size_t)(b * 4 + 0) * qs + 2 * H + h * hd;
    const float* v1 = v0 + qs; const float* v2 = v1 + qs; const float* v3 = v2 + qs;
    u16* orow = out + (size_t)(b * 4 + w) * H + h * hd;
    for (int i = l; i < hd; i += 64)
        orow[i] = f2bf(e0 * v0[i] + e1 * v1[i] + e2 * v2[i] + e3 * v3[i]);
}

// LN over 768: out = g*(x+res - m)*rinv + b, optional bf16 copy
__global__ __launch_bounds__(256) void ln768(
    const float* __restrict__ x, const float* __restrict__ res,
    const float* __restrict__ g, const float* __restrict__ be,
    float* __restrict__ out, u16* __restrict__ outb)
{
    int row = blockIdx.x, t = threadIdx.x;
    const float* xr = x + (size_t)row * 768;
    const float* rr = res + (size_t)row * 768;
    float v[3]; float s = 0.f, q = 0.f;
#pragma unroll
    for (int i = 0; i < 3; i++) {
        float a = xr[t + i * 256] + rr[t + i * 256];
        v[i] = a; s += a; q += a * a;
    }
    for (int off = 32; off; off >>= 1) { s += __shfl_down(s, off, 64); q += __shfl_down(q, off, 64); }
    __shared__ float ss[4], qq[4];
    int w = t >> 6, l = t & 63;
    if (l == 0) { ss[w] = s; qq[w] = q; }
    __syncthreads();
    s = ss[0] + ss[1] + ss[2] + ss[3];
    q = qq[0] + qq[1] + qq[2] + qq[3];
    float m = s * (1.f / 768.f);
    float ri = rsqrtf(q * (1.f / 768.f) - m * m + 1e-5f);
#pragma unroll
    for (int i = 0; i < 3; i++) {
        int c = t + i * 256;
        float o = g[c] * (v[i] - m) * ri + be[c];
        out[(size_t)row * 768 + c] = o;
        if (outb) outb[(size_t)row * 768 + c] = f2bf(o);
    }
}

// ---------------------------------------------------------------------------
// CSR build: cnt (atomics) -> exclusive scan (offs, cur) -> bucket fill
__global__ void edge_count(const int* __restrict__ ei, int* __restrict__ cnt, int E)
{
    int e = blockIdx.x * blockDim.x + threadIdx.x;
    if (e < E) atomicAdd(&cnt[ei[E + e]], 1);
}

__global__ __launch_bounds__(1024) void scan_offsets(
    const int* __restrict__ cnt, int* __restrict__ offs, int* __restrict__ cur, int n)
{
    __shared__ int part[1024];
    int t = threadIdx.x;
    int per = (n + 1023) / 1024;
    int base = t * per;
    int local = 0;
    for (int i = 0; i < per; i++) {
        int idx = base + i;
        if (idx < n) local += cnt[idx];
    }
    part[t] = local;
    __syncthreads();
    for (int off = 1; off < 1024; off <<= 1) {
        int v = (t >= off) ? part[t - off] : 0;
        __syncthreads();
        part[t] += v;
        __syncthreads();
    }
    int prefix = (t == 0) ? 0 : part[t - 1];
    for (int i = 0; i < per; i++) {
        int idx = base + i;
        if (idx < n) {
            offs[idx] = prefix;
            cur[idx] = prefix;
            prefix += cnt[idx];
        }
    }
}

__global__ void fill_edges(const int* __restrict__ ei, int* __restrict__ cur,
                           int* __restrict__ elist, int E)
{
    int e = blockIdx.x * blockDim.x + threadIdx.x;
    if (e < E) {
        int d = ei[E + e];
        int pos = atomicAdd(&cur[d], 1);
        elist[pos] = ei[e];    // src
    }
}

// aggN[d] = mean over in-edges of nodes2[src]; writes Abig cols 768:1536 (bf16).
// One wave per node; lane handles 12 contiguous cols (3x ushort4).
__global__ __launch_bounds__(256) void gather_mean(
    const int* __restrict__ offs, const int* __restrict__ cnt, const int* __restrict__ elist,
    u16* Abig, int Nn, int Mpad)
{
    int w = threadIdx.x >> 6, l = threadIdx.x & 63;
    int d = blockIdx.x * 4 + w;
    if (d >= Mpad) return;
    float acc[12];
#pragma unroll
    for (int j = 0; j < 12; j++) acc[j] = 0.f;
    float inv = 0.f;
    if (d < Nn) {
        int base = offs[d], c = cnt[d];
        for (int i = 0; i < c; i++) {
            int s = elist[base + i];
            const ushort4* p = (const ushort4*)(Abig + (size_t)s * 1536);
#pragma unroll
            for (int j4 = 0; j4 < 3; j4++) {
                ushort4 v = p[l * 3 + j4];
                acc[j4 * 4 + 0] += bf2f(v.x);
                acc[j4 * 4 + 1] += bf2f(v.y);
                acc[j4 * 4 + 2] += bf2f(v.z);
                acc[j4 * 4 + 3] += bf2f(v.w);
            }
        }
        inv = 1.f / (float)max(c, 1);
    }
    ushort4* q = (ushort4*)(Abig + (size_t)d * 1536 + 768);
#pragma unroll
    for (int j4 = 0; j4 < 3; j4++) {
        ushort4 o;
        o.x = f2bf(acc[j4 * 4 + 0] * inv);
        o.y = f2bf(acc[j4 * 4 + 1] * inv);
        o.z = f2bf(acc[j4 * 4 + 2] * inv);
        o.w = f2bf(acc[j4 * 4 + 3] * inv);
        q[l * 3 + j4] = o;
    }
}

// ---------------------------------------------------------------------------
// Fused: out2 readout (CSR pull over C2) + encoder layer 2 + tanh(l1) + l2.
// One block per batch (4 rows), wave w owns row w, 256 threads.
__global__ __launch_bounds__(256) void enc2_fused(
    const int* __restrict__ opt, const int* __restrict__ offs, const int* __restrict__ cnt,
    const int* __restrict__ elist, const float* __restrict__ C2, const float* __restrict__ bg,
    const float* __restrict__ w_qkv2, const float* __restrict__ b_qkv2,
    const float* __restrict__ w_o2, const float* __restrict__ b_o2,
    const float* __restrict__ g2a, const float* __restrict__ bb2a,
    const float* __restrict__ wf1, const float* __restrict__ bf1,
    const float* __restrict__ wf2, const float* __restrict__ bf2,
    const float* __restrict__ g2b, const float* __restrict__ bb2b,
    const float* __restrict__ w_l1, const float* __restrict__ b_l1,
    const float* __restrict__ w_l2, const float* __restrict__ b_l2,
    float* __restrict__ out)
{
    __shared__ float X[4][64];
    __shared__ float QKV[4][192];
    __shared__ float T[4][64];
    __shared__ float Hf[4][2048];
    int b = blockIdx.x;
    int w = threadIdx.x >> 6, l = threadIdx.x & 63;
    int row = b * 4 + w;

    // ---- GraphConv readout at option node: out2 = sum_in C2rel[src] + bg + C2root[d]
    {
        int d = opt[row];
        float acc = bg[l] + C2[(size_t)d * 128 + 64 + l];
        int base = offs[d], c = cnt[d];
        for (int i = 0; i < c; i++) {
            int s = elist[base + i];
            acc += C2[(size_t)s * 128 + l];
        }
        X[w][l] = acc;
    }
    __syncthreads();

    // ---- qkv (192 outs/row, 3 per lane)
#pragma unroll
    for (int j = 0; j < 3; j++) {
        int n = l + j * 64;
        const float* wr = w_qkv2 + (size_t)n * 64;
        float s = b_qkv2[n];
        for (int k = 0; k < 64; k++) s += X[w][k] * wr[k];
        QKV[w][n] = s;
    }
    __syncthreads();

    // ---- attention (nh=2, hd=32): lane l -> head l>>5, q elem = QKV[w][l]
    {
        float q = QKV[w][l];
        float sc0, sc1, sc2, sc3;
        {
            float p = q * QKV[0][64 + l];
#pragma unroll
            for (int off = 1; off < 32; off <<= 1) p += __shfl_xor(p, off, 64);
            sc0 = p * 0.1767766953f;
        }
        {
            float p = q * QKV[1][64 + l];
#pragma unroll
            for (int off = 1; off < 32; off <<= 1) p += __shfl_xor(p, off, 64);
            sc1 = p * 0.1767766953f;
        }
        {
            float p = q * QKV[2][64 + l];
#pragma unroll
            for (int off = 1; off < 32; off <<= 1) p += __shfl_xor(p, off, 64);
            sc2 = p * 0.1767766953f;
        }
        {
            float p = q * QKV[3][64 + l];
#pragma unroll
            for (int off = 1; off < 32; off <<= 1) p += __shfl_xor(p, off, 64);
            sc3 = p * 0.1767766953f;
        }
        float mx = fmaxf(fmaxf(sc0, sc1), fmaxf(sc2, sc3));
        float e0 = __expf(sc0 - mx), e1 = __expf(sc1 - mx), e2 = __expf(sc2 - mx), e3 = __expf(sc3 - mx);
        float inv = 1.f / (e0 + e1 + e2 + e3);
        T[w][l] = (e0 * QKV[0][128 + l] + e1 * QKV[1][128 + l] +
                   e2 * QKV[2][128 + l] + e3 * QKV[3][128 + l]) * inv;
    }
    __syncthreads();

    // ---- o-proj + residual + LN (g2a)
    {
        const float* wr = w_o2 + (size_t)l * 64;
        float s = b_o2[l];
        for (int k = 0; k < 64; k++) s += T[w][k] * wr[k];
        float xa = s + X[w][l];
        float sum = xa, sq = xa * xa;
#pragma unroll
        for (int off = 1; off < 64; off <<= 1) {
            sum += __shfl_xor(sum, off, 64);
            sq  += __shfl_xor(sq, off, 64);
        }
        float m = sum * (1.f / 64.f);
        float ri = rsqrtf(sq * (1.f / 64.f) - m * m + 1e-5f);
        float xn = g2a[l] * (xa - m) * ri + bb2a[l];
        __syncthreads();
        X[w][l] = xn;
    }
    __syncthreads();

    // ---- ff1: 2048 outs/row (32 per lane), relu
    for (int j = 0; j < 32; j++) {
        int n = l + j * 64;
        const float* wr = wf1 + (size_t)n * 64;
        float s = bf1[n];
        for (int k = 0; k < 64; k++) s += X[w][k] * wr[k];
        Hf[w][n] = fmaxf(s, 0.f);
    }
    __syncthreads();

    // ---- ff2: cooperative (all lanes per output n, coalesced weight reads)
    float myff = 0.f;
    for (int n = 0; n < 64; n++) {
        const float* wr = wf2 + (size_t)n * 2048;
        float p = 0.f;
#pragma unroll 8
        for (int j = 0; j < 32; j++) p += Hf[w][l + j * 64] * wr[l + j * 64];
#pragma unroll
        for (int off = 1; off < 64; off <<= 1) p += __shfl_xor(p, off, 64);
        if (l == n) myff = p;
    }
    myff += bf2[l];

    // ---- residual + LN (g2b)
    {
        float xa = X[w][l] + myff;
        float sum = xa, sq = xa * xa;
#pragma unroll
        for (int off = 1; off < 64; off <<= 1) {
            sum += __shfl_xor(sum, off, 64);
            sq  += __shfl_xor(sq, off, 64);
        }
        float m = sum * (1.f / 64.f);
        float ri = rsqrtf(sq * (1.f / 64.f) - m * m + 1e-5f);
        float xn = g2b[l] * (xa - m) * ri + bb2b[l];
        __syncthreads();
        X[w][l] = xn;
    }
    __syncthreads();

    // ---- l1 + tanh
    {
        const float* wr = w_l1 + (size_t)l * 64;
        float s = b_l1[l];
        for (int k = 0; k < 64; k++) s += X[w][k] * wr[k];
        T[w][l] = tanhf(s);
    }
    __syncthreads();

    // ---- l2 (single output per row)
    {
        float p = T[w][l] * w_l2[l];
#pragma unroll
        for (int off = 1; off < 64; off <<= 1) p += __shfl_xor(p, off, 64);
        if (l == 0) out[row] = p + b_l2[0];
    }
}

// ---------------------------------------------------------------------------
extern "C" void kernel_launch(void* const* d_in, const int* in_sizes, int n_in,
                              void* d_out, int out_size, void* d_ws, size_t ws_size,
                              hipStream_t stream)
{
    const float* nodes  = (const float*)d_in[0];
    const int*   ei     = (const int*)d_in[1];
    const int*   opt    = (const int*)d_in[2];
    const float* w_qkv1 = (const float*)d_in[3];
    const float* b_qkv1 = (const float*)d_in[4];
    const float* w_o1   = (const float*)d_in[5];
    const float* b_o1   = (const float*)d_in[6];
    const float* g1a    = (const float*)d_in[7];
    const float* bb1a   = (const float*)d_in[8];
    const float* w_ff1a = (const float*)d_in[9];
    const float* bf1a   = (const float*)d_in[10];
    const float* w_ff1b = (const float*)d_in[11];
    const float* bf1b   = (const float*)d_in[12];
    const float* g1b    = (const float*)d_in[13];
    const float* bb1b   = (const float*)d_in[14];
    // d_in[15..28]: wq..b6 — dead code (edge_type ≡ 0: softmax over singleton axis)
    const float* w_rel  = (const float*)d_in[29];
    const float* w_root = (const float*)d_in[30];
    const float* b_rgcn = (const float*)d_in[31];
    const float* wg_rel = (const float*)d_in[32];
    const float* wg_root= (const float*)d_in[33];
    const float* bg     = (const float*)d_in[34];
    const float* w_qkv2 = (const float*)d_in[35];
    const float* b_qkv2 = (const float*)d_in[36];
    const float* w_o2   = (const float*)d_in[37];
    const float* b_o2   = (const float*)d_in[38];
    const float* g2a    = (const float*)d_in[39];
    const float* bb2a   = (const float*)d_in[40];
    const float* w_ff2a = (const float*)d_in[41];
    const float* bf2a   = (const float*)d_in[42];
    const float* w_ff2b = (const float*)d_in[43];
    const float* bf2b   = (const float*)d_in[44];
    const float* g2b    = (const float*)d_in[45];
    const float* bb2b   = (const float*)d_in[46];
    const float* w_l1   = (const float*)d_in[47];
    const float* b_l1   = (const float*)d_in[48];
    const float* w_l2   = (const float*)d_in[49];
    const float* b_l2   = (const float*)d_in[50];

    const int H = 768, F = 2048;
    const int Nn = in_sizes[0] / H;            // 20000
    const int E  = in_sizes[1] / 2;            // 40000
    const int R  = in_sizes[2];                // 256 option rows
    const int Mpad = (Nn + 127) & ~127;        // 20096
    const int Bb = R / 4;                      // 64 batches

    char* ws = (char*)d_ws;
    size_t off = 0;
    auto alloc = [&](size_t b) -> char* {
        char* p = ws + off; off += (b + 255) & ~(size_t)255; return p;
    };
    // bf16 weights
    u16* wqkv1b  = (u16*)alloc((size_t)3 * H * H * 2);
    u16* wo1b    = (u16*)alloc((size_t)H * H * 2);
    u16* wff1ab  = (u16*)alloc((size_t)F * H * 2);
    u16* wff1bb  = (u16*)alloc((size_t)H * F * 2);
    u16* Wbt     = (u16*)alloc((size_t)768 * 1536 * 2);   // [w_root^T | w_rel0^T], row stride 1536
    u16* W2tb    = (u16*)alloc((size_t)128 * H * 2);      // [wg_rel^T ; wg_root^T]
    // encoder1 activations
    float* x0   = (float*)alloc((size_t)R * H * 4);
    u16*  x0b   = (u16*)alloc((size_t)R * H * 2);
    float* qkvb = (float*)alloc((size_t)R * 3 * H * 4);
    u16*  atnob = (u16*)alloc((size_t)R * H * 2);
    float* obuf = (float*)alloc((size_t)R * H * 4);
    float* x1   = (float*)alloc((size_t)R * H * 4);
    u16*  x1b   = (u16*)alloc((size_t)R * H * 2);
    u16*  ffhb  = (u16*)alloc((size_t)R * F * 2);
    float* ffo  = (float*)alloc((size_t)R * H * 4);
    float* x2   = (float*)alloc((size_t)R * H * 4);
    // big buffers
    u16*  Abig  = (u16*)alloc((size_t)Mpad * 1536 * 2);   // [nodes2 | aggN] bf16
    u16*  out1b = (u16*)alloc((size_t)Mpad * H * 2);
    float* C2   = (float*)alloc((size_t)Mpad * 128 * 4);
    // CSR
    int* cnt   = (int*)alloc((size_t)Nn * 4);
    int* offs  = (int*)alloc((size_t)Nn * 4);
    int* cur   = (int*)alloc((size_t)Nn * 4);
    int* elist = (int*)alloc((size_t)E * 4);
    (void)ws_size; (void)n_in; (void)out_size;

    // ---- weight prep (1 conv dispatch + 1 transpose dispatch) ----
    {
        CJobs4 cj;
        cj.j[0] = { w_qkv1, wqkv1b, (long)3 * H * H / 4 };
        cj.j[1] = { w_o1,   wo1b,   (long)H * H / 4 };
        cj.j[2] = { w_ff1a, wff1ab, (long)F * H / 4 };
        cj.j[3] = { w_ff1b, wff1bb, (long)H * F / 4 };
        conv4_bf16<<<dim3(432, 1, 4), 256, 0, stream>>>(cj);
        TJobs4 tj;
        tj.j[0] = { w_root, Wbt,        768, 768, 1536 };  // Wbt[n,0:768]   = w_root[:,n]
        tj.j[1] = { w_rel,  Wbt + 768,  768, 768, 1536 };  // Wbt[n,768:1536]= w_rel0[:,n]
        tj.j[2] = { wg_rel, W2tb,               768, 64, 768 };
        tj.j[3] = { wg_root, W2tb + (size_t)64 * 768, 768, 64, 768 };
        transpose4_bf16<<<dim3(24, 24, 4), dim3(32, 8), 0, stream>>>(tj);
    }

    // ---- encoder layer 1 on option nodes (256 x 768) ----
    gather_x0<<<R, 256, 0, stream>>>(nodes, opt, x0, x0b, H);
    gemm_bt<<<dim3(3 * H / 128, R / 128), 256, 0, stream>>>(x0b, wqkv1b, qkvb, nullptr, b_qkv1, R, 3 * H, H, 0);
    attn_small_b<<<Bb * 2, 256, 0, stream>>>(qkvb, atnob, H, 2, H / 2);
    gemm_bt<<<dim3(H / 128, R / 128), 256, 0, stream>>>(atnob, wo1b, obuf, nullptr, b_o1, R, H, H, 0);
    ln768<<<R, 256, 0, stream>>>(obuf, x0, g1a, bb1a, x1, x1b);
    gemm_bt<<<dim3(F / 128, R / 128), 256, 0, stream>>>(x1b, wff1ab, nullptr, ffhb, bf1a, R, F, H, 1);
    gemm_bt<<<dim3(H / 128, R / 128), 256, 0, stream>>>(ffhb, wff1bb, ffo, nullptr, bf1b, R, H, F, 0);
    ln768<<<R, 256, 0, stream>>>(ffo, x1, g1b, bb1b, x2, nullptr);

    // ---- nodes2 into Abig cols 0:768 (bf16, padded) ----
    conv_nodes_str<<<2048, 256, 0, stream>>>(nodes, Abig, Nn, Mpad);
    scatter_opts_str<<<R, 256, 0, stream>>>(x2, opt, Abig);

    // ---- CSR build + mean-aggregate nodes2 into Abig cols 768:1536 ----
    hipMemsetAsync(cnt, 0, (size_t)Nn * 4, stream);
    edge_count<<<(E + 255) / 256, 256, 0, stream>>>(ei, cnt, E);
    scan_offsets<<<1, 1024, 0, stream>>>(cnt, offs, cur, Nn);
    fill_edges<<<(E + 255) / 256, 256, 0, stream>>>(ei, cur, elist, E);
    gather_mean<<<Mpad / 4, 256, 0, stream>>>(offs, cnt, elist, Abig, Nn, Mpad);

    // ---- RGCN(rel0)+root as ONE K=1536 GEMM, bf16 out ----
    gemm_bt<<<dim3(H / 128, Mpad / 128), 256, 0, stream>>>(Abig, Wbt, nullptr, out1b, b_rgcn, Mpad, H, 1536, 0);

    // ---- GraphConv projection (segment_sum commutes with matmul) ----
    gemm_bt<<<dim3(1, Mpad / 128), 256, 0, stream>>>(out1b, W2tb, C2, nullptr, nullptr, Mpad, 128, 768, 0);

    // ---- fused out2-readout + encoder2 + head ----
    enc2_fused<<<Bb, 256, 0, stream>>>(opt, offs, cnt, elist, C2, bg,
                                       w_qkv2, b_qkv2, w_o2, b_o2, g2a, bb2a,
                                       w_ff2a, bf2a, w_ff2b, bf2b, g2b, bb2b,
                                       w_l1, b_l1, w_l2, b_l2, (float*)d_out);
}

// Round 5
// 570.786 us; speedup vs baseline: 1.2628x; 1.2628x over previous
//
#include <hip/hip_runtime.h>

typedef unsigned short u16;
typedef unsigned int u32;
typedef __bf16 bf16x8 __attribute__((ext_vector_type(8)));
typedef float f32x4 __attribute__((ext_vector_type(4)));

__device__ __forceinline__ u16 f2bf(float f) {
    union { float f; u32 u; } v; v.f = f;
    u32 r = v.u + 0x7FFFu + ((v.u >> 16) & 1u);   // RNE
    return (u16)(r >> 16);
}
__device__ __forceinline__ float bf2f(u16 h) {
    union { u32 u; float f; } v; v.u = (u32)h << 16; return v.f;
}

// ---------------------------------------------------------------------------
// bf16 GEMM: C[M,N] = A[M,K] @ Bt[N,K]^T (+bias, optional relu)
// If Cb != null, writes bf16 output there instead of fp32 C.
// 128x128 tile, BK=64, 4 waves, 16x16x32 MFMA, global_load_lds width 16,
// XOR-swizzled LDS (chunk ^= row&7). M%128==0, N%128==0, K%64==0.
// ---------------------------------------------------------------------------
__global__ __launch_bounds__(256) void gemm_bt(
    const u16* __restrict__ A, const u16* __restrict__ Bt,
    float* __restrict__ C, u16* __restrict__ Cb, const float* __restrict__ bias,
    int M, int N, int K, int relu)
{
    __shared__ char lA[128 * 64 * 2];
    __shared__ char lB[128 * 64 * 2];
    const int t = threadIdx.x;
    const int w = t >> 6, l = t & 63;
    const int bn = blockIdx.x, bm = blockIdx.y;
    const int wr = w >> 1, wc = w & 1;

    const int srow = w * 8 + (l >> 3);
    const int scol = ((l & 7) ^ (l >> 3)) << 3;     // pre-swizzled source chunk
    const u16* gA = A + (size_t)(bm * 128 + srow) * K + scol;
    const u16* gB = Bt + (size_t)(bn * 128 + srow) * K + scol;

    f32x4 zero = {0.f, 0.f, 0.f, 0.f};
    f32x4 acc[4][4];
#pragma unroll
    for (int i = 0; i < 4; i++)
#pragma unroll
        for (int j = 0; j < 4; j++) acc[i][j] = zero;

    const int arow = wr * 64 + (l & 15);
    const int brow = wc * 64 + (l & 15);
    const int kx = l >> 4;
    const int sw = l & 7;       // == row&7 for fragment rows

    for (int k0 = 0; k0 < K; k0 += 64) {
#pragma unroll
        for (int c2 = 0; c2 < 4; ++c2) {
            __builtin_amdgcn_global_load_lds(
                (const __attribute__((address_space(1))) void*)(gA + (size_t)c2 * 32 * K + k0),
                (__attribute__((address_space(3))) void*)(lA + c2 * 4096 + w * 1024), 16, 0, 0);
            __builtin_amdgcn_global_load_lds(
                (const __attribute__((address_space(1))) void*)(gB + (size_t)c2 * 32 * K + k0),
                (__attribute__((address_space(3))) void*)(lB + c2 * 4096 + w * 1024), 16, 0, 0);
        }
        __syncthreads();
#pragma unroll
        for (int kk = 0; kk < 2; ++kk) {
            bf16x8 af[4], bfr[4];
#pragma unroll
            for (int mi = 0; mi < 4; ++mi)
                af[mi] = *(const bf16x8*)(lA + (arow + mi * 16) * 128 + (((kk * 4 + kx) ^ sw) << 4));
#pragma unroll
            for (int ni = 0; ni < 4; ++ni)
                bfr[ni] = *(const bf16x8*)(lB + (brow + ni * 16) * 128 + (((kk * 4 + kx) ^ sw) << 4));
#pragma unroll
            for (int mi = 0; mi < 4; ++mi)
#pragma unroll
                for (int ni = 0; ni < 4; ++ni)
                    acc[mi][ni] = __builtin_amdgcn_mfma_f32_16x16x32_bf16(af[mi], bfr[ni], acc[mi][ni], 0, 0, 0);
        }
        __syncthreads();
    }

    const int cm = bm * 128 + wr * 64;
    const int cn = bn * 128 + wc * 64;
#pragma unroll
    for (int mi = 0; mi < 4; ++mi) {
#pragma unroll
        for (int ni = 0; ni < 4; ++ni) {
            int row0 = cm + mi * 16 + (l >> 4) * 4;
            int col = cn + ni * 16 + (l & 15);
            float bv = bias ? bias[col] : 0.f;
#pragma unroll
            for (int r = 0; r < 4; ++r) {
                float v = acc[mi][ni][r] + bv;
                if (relu) v = fmaxf(v, 0.f);
                if (Cb) Cb[(size_t)(row0 + r) * N + col] = f2bf(v);
                else    C [(size_t)(row0 + r) * N + col] = v;
            }
        }
    }
}

// ---------------------------------------------------------------------------
// batched fp32 -> bf16 weight conversion (4 jobs, blockIdx.z selects)
struct CJob { const float* src; u16* dst; long n4; };
struct CJobs4 { CJob j[4]; };
__global__ void conv4_bf16(CJobs4 jobs)
{
    CJob jb = jobs.j[blockIdx.z];
    long i = (long)blockIdx.x * blockDim.x + threadIdx.x;
    long stride = (long)gridDim.x * blockDim.x;
    for (; i < jb.n4; i += stride) {
        float4 v = ((const float4*)jb.src)[i];
        ushort4 o;
        o.x = f2bf(v.x); o.y = f2bf(v.y); o.z = f2bf(v.z); o.w = f2bf(v.w);
        ((ushort4*)jb.dst)[i] = o;
    }
}

// batched transpose fp32 [Rr,Cc] -> bf16 out[c*ldo + r]
struct TJob { const float* src; u16* dst; int Rr, Cc, ldo; };
struct TJobs4 { TJob j[4]; };
__global__ void transpose4_bf16(TJobs4 jobs)
{
    TJob jb = jobs.j[blockIdx.z];
    __shared__ float tile[32][33];
    int c0 = blockIdx.x * 32, r0 = blockIdx.y * 32;
    if (c0 >= jb.Cc || r0 >= jb.Rr) return;
    int tx = threadIdx.x, ty = threadIdx.y;
    for (int dy = 0; dy < 32; dy += 8) {
        int r = r0 + ty + dy, c = c0 + tx;
        tile[ty + dy][tx] = (r < jb.Rr && c < jb.Cc) ? jb.src[(size_t)r * jb.Cc + c] : 0.f;
    }
    __syncthreads();
    for (int dy = 0; dy < 32; dy += 8) {
        int c = c0 + ty + dy, r = r0 + tx;
        if (c < jb.Cc && r < jb.Rr) jb.dst[(size_t)c * jb.ldo + r] = f2bf(tile[tx][ty + dy]);
    }
}

// nodes fp32 [Nn,768] -> bf16 into Abig[Mpad,1536] cols 0:768, pad rows zero
__global__ void conv_nodes_str(const float* __restrict__ nodes, u16* __restrict__ Abig,
                               int Nn, int Mpad)
{
    long i = (long)blockIdx.x * blockDim.x + threadIdx.x;
    long stride = (long)gridDim.x * blockDim.x;
    long n4 = (long)Mpad * 192;     // float4 groups over [Mpad,768]
    for (; i < n4; i += stride) {
        long row = i / 192, c4 = i % 192;
        ushort4 o;
        if ((int)row < Nn) {
            float4 v = ((const float4*)nodes)[i];
            o.x = f2bf(v.x); o.y = f2bf(v.y); o.z = f2bf(v.z); o.w = f2bf(v.w);
        } else { o.x = 0; o.y = 0; o.z = 0; o.w = 0; }
        ((ushort4*)Abig)[row * 384 + c4] = o;
    }
}

__global__ void gather_x0(const float* __restrict__ nodes, const int* __restrict__ opt,
                          float* __restrict__ x0, u16* __restrict__ x0b, int H)
{
    int r = blockIdx.x;
    size_t srcb = (size_t)opt[r] * H;
    for (int c = threadIdx.x; c < H; c += blockDim.x) {
        float v = nodes[srcb + c];
        x0[(size_t)r * H + c] = v;
        x0b[(size_t)r * H + c] = f2bf(v);
    }
}

// x2 fp32 [R,768] -> Abig rows opt[r], cols 0:768 (bf16)
__global__ void scatter_opts_str(const float* __restrict__ x2, const int* __restrict__ opt,
                                 u16* __restrict__ Abig)
{
    int r = blockIdx.x;
    size_t dstb = (size_t)opt[r] * 1536;
    for (int c = threadIdx.x; c < 768; c += blockDim.x)
        Abig[dstb + c] = f2bf(x2[(size_t)r * 768 + c]);
}

// S=4 attention (enc1), bf16 out; one block per (batch,head), wave w = query row
__global__ __launch_bounds__(256) void attn_small_b(
    const float* __restrict__ qkv, u16* __restrict__ out, int H, int nh, int hd)
{
    int b = blockIdx.x / nh, h = blockIdx.x % nh;
    int w = threadIdx.x >> 6, l = threadIdx.x & 63;
    __shared__ float sc[4][4];
    int qs = 3 * H;
    const float* qr = qkv + (size_t)(b * 4 + w) * qs + h * hd;
    float scale = rsqrtf((float)hd);
    for (int sj = 0; sj < 4; ++sj) {
        const float* kr = qkv + (size_t)(b * 4 + sj) * qs + H + h * hd;
        float p = 0.f;
        for (int i = l; i < hd; i += 64) p += qr[i] * kr[i];
        for (int off = 32; off; off >>= 1) p += __shfl_down(p, off, 64);
        if (l == 0) sc[w][sj] = p * scale;
    }
    __syncthreads();
    float a0 = sc[w][0], a1 = sc[w][1], a2 = sc[w][2], a3 = sc[w][3];
    float mx = fmaxf(fmaxf(a0, a1), fmaxf(a2, a3));
    float e0 = __expf(a0 - mx), e1 = __expf(a1 - mx), e2 = __expf(a2 - mx), e3 = __expf(a3 - mx);
    float inv = 1.f / (e0 + e1 + e2 + e3);
    e0 *= inv; e1 *= inv; e2 *= inv; e3 *= inv;
    const float* v0 = qkv + (size_t)(b * 4 + 0) * qs + 2 * H + h * hd;
    const float* v1 = v0 + qs; const float* v2 = v1 + qs; const float* v3 = v2 + qs;
    u16* orow = out + (size_t)(b * 4 + w) * H + h * hd;
    for (int i = l; i < hd; i += 64)
        orow[i] = f2bf(e0 * v0[i] + e1 * v1[i] + e2 * v2[i] + e3 * v3[i]);
}

// LN over 768: out = g*(x+res - m)*rinv + b, optional bf16 copy
__global__ __launch_bounds__(256) void ln768(
    const float* __restrict__ x, const float* __restrict__ res,
    const float* __restrict__ g, const float* __restrict__ be,
    float* __restrict__ out, u16* __restrict__ outb)
{
    int row = blockIdx.x, t = threadIdx.x;
    const float* xr = x + (size_t)row * 768;
    const float* rr = res + (size_t)row * 768;
    float v[3]; float s = 0.f, q = 0.f;
#pragma unroll
    for (int i = 0; i < 3; i++) {
        float a = xr[t + i * 256] + rr[t + i * 256];
        v[i] = a; s += a; q += a * a;
    }
    for (int off = 32; off; off >>= 1) { s += __shfl_down(s, off, 64); q += __shfl_down(q, off, 64); }
    __shared__ float ss[4], qq[4];
    int w = t >> 6, l = t & 63;
    if (l == 0) { ss[w] = s; qq[w] = q; }
    __syncthreads();
    s = ss[0] + ss[1] + ss[2] + ss[3];
    q = qq[0] + qq[1] + qq[2] + qq[3];
    float m = s * (1.f / 768.f);
    float ri = rsqrtf(q * (1.f / 768.f) - m * m + 1e-5f);
#pragma unroll
    for (int i = 0; i < 3; i++) {
        int c = t + i * 256;
        float o = g[c] * (v[i] - m) * ri + be[c];
        out[(size_t)row * 768 + c] = o;
        if (outb) outb[(size_t)row * 768 + c] = f2bf(o);
    }
}

// ---------------------------------------------------------------------------
// CSR build: cnt (atomics) -> exclusive scan (offs, cur) -> bucket fill
__global__ void edge_count(const int* __restrict__ ei, int* __restrict__ cnt, int E)
{
    int e = blockIdx.x * blockDim.x + threadIdx.x;
    if (e < E) atomicAdd(&cnt[ei[E + e]], 1);
}

__global__ __launch_bounds__(1024) void scan_offsets(
    const int* __restrict__ cnt, int* __restrict__ offs, int* __restrict__ cur, int n)
{
    __shared__ int part[1024];
    int t = threadIdx.x;
    int per = (n + 1023) / 1024;
    int base = t * per;
    int local = 0;
    for (int i = 0; i < per; i++) {
        int idx = base + i;
        if (idx < n) local += cnt[idx];
    }
    part[t] = local;
    __syncthreads();
    for (int off = 1; off < 1024; off <<= 1) {
        int v = (t >= off) ? part[t - off] : 0;
        __syncthreads();
        part[t] += v;
        __syncthreads();
    }
    int prefix = (t == 0) ? 0 : part[t - 1];
    for (int i = 0; i < per; i++) {
        int idx = base + i;
        if (idx < n) {
            offs[idx] = prefix;
            cur[idx] = prefix;
            prefix += cnt[idx];
        }
    }
}

__global__ void fill_edges(const int* __restrict__ ei, int* __restrict__ cur,
                           int* __restrict__ elist, int E)
{
    int e = blockIdx.x * blockDim.x + threadIdx.x;
    if (e < E) {
        int d = ei[E + e];
        int pos = atomicAdd(&cur[d], 1);
        elist[pos] = ei[e];    // src
    }
}

// aggN[d] = mean over in-edges of nodes2[src]; writes Abig cols 768:1536 (bf16).
__global__ __launch_bounds__(256) void gather_mean(
    const int* __restrict__ offs, const int* __restrict__ cnt, const int* __restrict__ elist,
    u16* Abig, int Nn, int Mpad)
{
    int w = threadIdx.x >> 6, l = threadIdx.x & 63;
    int d = blockIdx.x * 4 + w;
    if (d >= Mpad) return;
    float acc[12];
#pragma unroll
    for (int j = 0; j < 12; j++) acc[j] = 0.f;
    float inv = 0.f;
    if (d < Nn) {
        int base = offs[d], c = cnt[d];
        for (int i = 0; i < c; i++) {
            int s = elist[base + i];
            const ushort4* p = (const ushort4*)(Abig + (size_t)s * 1536);
#pragma unroll
            for (int j4 = 0; j4 < 3; j4++) {
                ushort4 v = p[l * 3 + j4];
                acc[j4 * 4 + 0] += bf2f(v.x);
                acc[j4 * 4 + 1] += bf2f(v.y);
                acc[j4 * 4 + 2] += bf2f(v.z);
                acc[j4 * 4 + 3] += bf2f(v.w);
            }
        }
        inv = 1.f / (float)max(c, 1);
    }
    ushort4* q = (ushort4*)(Abig + (size_t)d * 1536 + 768);
#pragma unroll
    for (int j4 = 0; j4 < 3; j4++) {
        ushort4 o;
        o.x = f2bf(acc[j4 * 4 + 0] * inv);
        o.y = f2bf(acc[j4 * 4 + 1] * inv);
        o.z = f2bf(acc[j4 * 4 + 2] * inv);
        o.w = f2bf(acc[j4 * 4 + 3] * inv);
        q[l * 3 + j4] = o;
    }
}

// ---------------------------------------------------------------------------
// Tail, split for parallelism (round-5: the 205µs fused kernel was
// occupancy-starved at 64 blocks / VALUBusy 1.3%).
// enc2_head: out2 readout + qkv + attn + o-proj + LN(g2a) -> x21 [256,64]
__global__ __launch_bounds__(256) void enc2_head(
    const int* __restrict__ opt, const int* __restrict__ offs, const int* __restrict__ cnt,
    const int* __restrict__ elist, const float* __restrict__ C2, const float* __restrict__ bg,
    const float* __restrict__ w_qkv2, const float* __restrict__ b_qkv2,
    const float* __restrict__ w_o2, const float* __restrict__ b_o2,
    const float* __restrict__ g2a, const float* __restrict__ bb2a,
    float* __restrict__ x21)
{
    __shared__ float X[4][64];
    __shared__ float QKV[4][192];
    __shared__ float T[4][64];
    int b = blockIdx.x;
    int w = threadIdx.x >> 6, l = threadIdx.x & 63;
    int row = b * 4 + w;

    // GraphConv readout at option node: sum_in C2rel[src] + bg + C2root[d]
    {
        int d = opt[row];
        float acc = bg[l] + C2[(size_t)d * 128 + 64 + l];
        int base = offs[d], c = cnt[d];
        for (int i = 0; i < c; i++) {
            int s = elist[base + i];
            acc += C2[(size_t)s * 128 + l];
        }
        X[w][l] = acc;
    }
    __syncthreads();

    // qkv (192 outs/row, 3 per lane)
#pragma unroll
    for (int j = 0; j < 3; j++) {
        int n = l + j * 64;
        const float* wr = w_qkv2 + (size_t)n * 64;
        float s = b_qkv2[n];
        for (int k = 0; k < 64; k++) s += X[w][k] * wr[k];
        QKV[w][n] = s;
    }
    __syncthreads();

    // attention (nh=2, hd=32): lane l -> head l>>5
    {
        float q = QKV[w][l];
        float p0 = q * QKV[0][64 + l], p1 = q * QKV[1][64 + l];
        float p2 = q * QKV[2][64 + l], p3 = q * QKV[3][64 + l];
#pragma unroll
        for (int off = 1; off < 32; off <<= 1) {
            p0 += __shfl_xor(p0, off, 64); p1 += __shfl_xor(p1, off, 64);
            p2 += __shfl_xor(p2, off, 64); p3 += __shfl_xor(p3, off, 64);
        }
        p0 *= 0.1767766953f; p1 *= 0.1767766953f; p2 *= 0.1767766953f; p3 *= 0.1767766953f;
        float mx = fmaxf(fmaxf(p0, p1), fmaxf(p2, p3));
        float e0 = __expf(p0 - mx), e1 = __expf(p1 - mx), e2 = __expf(p2 - mx), e3 = __expf(p3 - mx);
        float inv = 1.f / (e0 + e1 + e2 + e3);
        T[w][l] = (e0 * QKV[0][128 + l] + e1 * QKV[1][128 + l] +
                   e2 * QKV[2][128 + l] + e3 * QKV[3][128 + l]) * inv;
    }
    __syncthreads();

    // o-proj + residual + LN (g2a)
    {
        const float* wr = w_o2 + (size_t)l * 64;
        float s = b_o2[l];
        for (int k = 0; k < 64; k++) s += T[w][k] * wr[k];
        float xa = s + X[w][l];
        float sum = xa, sq = xa * xa;
#pragma unroll
        for (int off = 1; off < 64; off <<= 1) {
            sum += __shfl_xor(sum, off, 64);
            sq  += __shfl_xor(sq, off, 64);
        }
        float m = sum * (1.f / 64.f);
        float ri = rsqrtf(sq * (1.f / 64.f) - m * m + 1e-5f);
        x21[(size_t)row * 64 + l] = g2a[l] * (xa - m) * ri + bb2a[l];
    }
}

// ff1: Hf[r,n] = relu(x21[r,:]·wf1[n,:] + bf1[n]); one output per thread.
// grid = R*8 blocks: r = b>>3, n = (b&7)*256 + t.
__global__ __launch_bounds__(256) void ff1_par(
    const float* __restrict__ x21, const float* __restrict__ wf1,
    const float* __restrict__ bf1, float* __restrict__ Hf)
{
    __shared__ float X[64];
    int b = blockIdx.x, t = threadIdx.x;
    int r = b >> 3, n = (b & 7) * 256 + t;
    if (t < 64) X[t] = x21[(size_t)r * 64 + t];
    __syncthreads();
    const float4* wr4 = (const float4*)(wf1 + (size_t)n * 64);
    float s = bf1[n];
#pragma unroll
    for (int k4 = 0; k4 < 16; k4++) {
        float4 wv = wr4[k4];
        const float* xp = X + k4 * 4;
        s += wv.x * xp[0] + wv.y * xp[1] + wv.z * xp[2] + wv.w * xp[3];
    }
    Hf[(size_t)r * 2048 + n] = fmaxf(s, 0.f);
}

// ff2 + residual + LN(g2b) + l1 + tanh + l2. One block per row, 4 waves.
// Wave w covers K-range [w*512, w*512+512); lane l owns output n=l.
__global__ __launch_bounds__(256) void ff2_tail(
    const float* __restrict__ Hf, const float* __restrict__ x21,
    const float* __restrict__ wf2, const float* __restrict__ bf2,
    const float* __restrict__ g2b, const float* __restrict__ bb2b,
    const float* __restrict__ w_l1, const float* __restrict__ b_l1,
    const float* __restrict__ w_l2, const float* __restrict__ b_l2,
    float* __restrict__ out)
{
    __shared__ float HL[2048];
    __shared__ float part[4][64];
    __shared__ float X2[64];
    int r = blockIdx.x, t = threadIdx.x;
    int w = t >> 6, l = t & 63;

    // stage Hf row (coalesced float4)
    {
        const float4* src = (const float4*)(Hf + (size_t)r * 2048);
        float4* dst = (float4*)HL;
        dst[t] = src[t];          // 256 threads x 16B = 4KB
        dst[t + 256] = src[t + 256];
    }
    __syncthreads();

    // partial dot: wave w, lane l: sum over k in [w*512, w*512+512) of HL[k]*wf2[l][k]
    {
        const float4* wr4 = (const float4*)(wf2 + (size_t)l * 2048 + w * 512);
        const float* hp = HL + w * 512;
        float s = 0.f;
#pragma unroll 16
        for (int k4 = 0; k4 < 128; k4++) {
            float4 wv = wr4[k4];
            const float* xp = hp + k4 * 4;
            s += wv.x * xp[0] + wv.y * xp[1] + wv.z * xp[2] + wv.w * xp[3];
        }
        part[w][l] = s;
    }
    __syncthreads();

    if (w == 0) {
        // combine partials + bias + residual + LN(g2b)
        float xa = part[0][l] + part[1][l] + part[2][l] + part[3][l] + bf2[l]
                 + x21[(size_t)r * 64 + l];
        float sum = xa, sq = xa * xa;
#pragma unroll
        for (int off = 1; off < 64; off <<= 1) {
            sum += __shfl_xor(sum, off, 64);
            sq  += __shfl_xor(sq, off, 64);
        }
        float m = sum * (1.f / 64.f);
        float ri = rsqrtf(sq * (1.f / 64.f) - m * m + 1e-5f);
        X2[l] = g2b[l] * (xa - m) * ri + bb2b[l];
        __builtin_amdgcn_wave_barrier();
        // l1 + tanh
        const float* wr = w_l1 + (size_t)l * 64;
        float s = b_l1[l];
        for (int k = 0; k < 64; k++) s += X2[k] * wr[k];
        float tv = tanhf(s);
        // l2 reduce
        float p = tv * w_l2[l];
#pragma unroll
        for (int off = 1; off < 64; off <<= 1) p += __shfl_xor(p, off, 64);
        if (l == 0) out[r] = p + b_l2[0];
    }
}

// ---------------------------------------------------------------------------
extern "C" void kernel_launch(void* const* d_in, const int* in_sizes, int n_in,
                              void* d_out, int out_size, void* d_ws, size_t ws_size,
                              hipStream_t stream)
{
    const float* nodes  = (const float*)d_in[0];
    const int*   ei     = (const int*)d_in[1];
    const int*   opt    = (const int*)d_in[2];
    const float* w_qkv1 = (const float*)d_in[3];
    const float* b_qkv1 = (const float*)d_in[4];
    const float* w_o1   = (const float*)d_in[5];
    const float* b_o1   = (const float*)d_in[6];
    const float* g1a    = (const float*)d_in[7];
    const float* bb1a   = (const float*)d_in[8];
    const float* w_ff1a = (const float*)d_in[9];
    const float* bf1a   = (const float*)d_in[10];
    const float* w_ff1b = (const float*)d_in[11];
    const float* bf1b   = (const float*)d_in[12];
    const float* g1b    = (const float*)d_in[13];
    const float* bb1b   = (const float*)d_in[14];
    // d_in[15..28]: wq..b6 — dead code (edge_type ≡ 0: softmax over singleton axis)
    const float* w_rel  = (const float*)d_in[29];
    const float* w_root = (const float*)d_in[30];
    const float* b_rgcn = (const float*)d_in[31];
    const float* wg_rel = (const float*)d_in[32];
    const float* wg_root= (const float*)d_in[33];
    const float* bg     = (const float*)d_in[34];
    const float* w_qkv2 = (const float*)d_in[35];
    const float* b_qkv2 = (const float*)d_in[36];
    const float* w_o2   = (const float*)d_in[37];
    const float* b_o2   = (const float*)d_in[38];
    const float* g2a    = (const float*)d_in[39];
    const float* bb2a   = (const float*)d_in[40];
    const float* w_ff2a = (const float*)d_in[41];
    const float* bf2a   = (const float*)d_in[42];
    const float* w_ff2b = (const float*)d_in[43];
    const float* bf2b   = (const float*)d_in[44];
    const float* g2b    = (const float*)d_in[45];
    const float* bb2b   = (const float*)d_in[46];
    const float* w_l1   = (const float*)d_in[47];
    const float* b_l1   = (const float*)d_in[48];
    const float* w_l2   = (const float*)d_in[49];
    const float* b_l2   = (const float*)d_in[50];

    const int H = 768, F = 2048;
    const int Nn = in_sizes[0] / H;            // 20000
    const int E  = in_sizes[1] / 2;            // 40000
    const int R  = in_sizes[2];                // 256 option rows
    const int Mpad = (Nn + 127) & ~127;        // 20096
    const int Bb = R / 4;                      // 64 batches

    char* ws = (char*)d_ws;
    size_t off = 0;
    auto alloc = [&](size_t b) -> char* {
        char* p = ws + off; off += (b + 255) & ~(size_t)255; return p;
    };
    // bf16 weights
    u16* wqkv1b  = (u16*)alloc((size_t)3 * H * H * 2);
    u16* wo1b    = (u16*)alloc((size_t)H * H * 2);
    u16* wff1ab  = (u16*)alloc((size_t)F * H * 2);
    u16* wff1bb  = (u16*)alloc((size_t)H * F * 2);
    u16* Wbt     = (u16*)alloc((size_t)768 * 1536 * 2);   // [w_root^T | w_rel0^T], row stride 1536
    u16* W2tb    = (u16*)alloc((size_t)128 * H * 2);      // [wg_rel^T ; wg_root^T]
    // encoder1 activations
    float* x0   = (float*)alloc((size_t)R * H * 4);
    u16*  x0b   = (u16*)alloc((size_t)R * H * 2);
    float* qkvb = (float*)alloc((size_t)R * 3 * H * 4);
    u16*  atnob = (u16*)alloc((size_t)R * H * 2);
    float* obuf = (float*)alloc((size_t)R * H * 4);
    float* x1   = (float*)alloc((size_t)R * H * 4);
    u16*  x1b   = (u16*)alloc((size_t)R * H * 2);
    u16*  ffhb  = (u16*)alloc((size_t)R * F * 2);
    float* ffo  = (float*)alloc((size_t)R * H * 4);
    float* x2   = (float*)alloc((size_t)R * H * 4);
    // big buffers
    u16*  Abig  = (u16*)alloc((size_t)Mpad * 1536 * 2);   // [nodes2 | aggN] bf16
    u16*  out1b = (u16*)alloc((size_t)Mpad * H * 2);
    float* C2   = (float*)alloc((size_t)Mpad * 128 * 4);
    // CSR
    int* cnt   = (int*)alloc((size_t)Nn * 4);
    int* offs  = (int*)alloc((size_t)Nn * 4);
    int* cur   = (int*)alloc((size_t)Nn * 4);
    int* elist = (int*)alloc((size_t)E * 4);
    // tail
    float* x21 = (float*)alloc((size_t)R * 64 * 4);
    float* Hf2 = (float*)alloc((size_t)R * F * 4);
    (void)ws_size; (void)n_in; (void)out_size;

    // ---- weight prep ----
    {
        CJobs4 cj;
        cj.j[0] = { w_qkv1, wqkv1b, (long)3 * H * H / 4 };
        cj.j[1] = { w_o1,   wo1b,   (long)H * H / 4 };
        cj.j[2] = { w_ff1a, wff1ab, (long)F * H / 4 };
        cj.j[3] = { w_ff1b, wff1bb, (long)H * F / 4 };
        conv4_bf16<<<dim3(432, 1, 4), 256, 0, stream>>>(cj);
        TJobs4 tj;
        tj.j[0] = { w_root, Wbt,        768, 768, 1536 };  // Wbt[n,0:768]   = w_root[:,n]
        tj.j[1] = { w_rel,  Wbt + 768,  768, 768, 1536 };  // Wbt[n,768:1536]= w_rel0[:,n]
        tj.j[2] = { wg_rel, W2tb,               768, 64, 768 };
        tj.j[3] = { wg_root, W2tb + (size_t)64 * 768, 768, 64, 768 };
        transpose4_bf16<<<dim3(24, 24, 4), dim3(32, 8), 0, stream>>>(tj);
    }

    // ---- encoder layer 1 on option nodes (256 x 768) ----
    gather_x0<<<R, 256, 0, stream>>>(nodes, opt, x0, x0b, H);
    gemm_bt<<<dim3(3 * H / 128, R / 128), 256, 0, stream>>>(x0b, wqkv1b, qkvb, nullptr, b_qkv1, R, 3 * H, H, 0);
    attn_small_b<<<Bb * 2, 256, 0, stream>>>(qkvb, atnob, H, 2, H / 2);
    gemm_bt<<<dim3(H / 128, R / 128), 256, 0, stream>>>(atnob, wo1b, obuf, nullptr, b_o1, R, H, H, 0);
    ln768<<<R, 256, 0, stream>>>(obuf, x0, g1a, bb1a, x1, x1b);
    gemm_bt<<<dim3(F / 128, R / 128), 256, 0, stream>>>(x1b, wff1ab, nullptr, ffhb, bf1a, R, F, H, 1);
    gemm_bt<<<dim3(H / 128, R / 128), 256, 0, stream>>>(ffhb, wff1bb, ffo, nullptr, bf1b, R, H, F, 0);
    ln768<<<R, 256, 0, stream>>>(ffo, x1, g1b, bb1b, x2, nullptr);

    // ---- nodes2 into Abig cols 0:768 (bf16, padded) ----
    conv_nodes_str<<<2048, 256, 0, stream>>>(nodes, Abig, Nn, Mpad);
    scatter_opts_str<<<R, 256, 0, stream>>>(x2, opt, Abig);

    // ---- CSR build + mean-aggregate nodes2 into Abig cols 768:1536 ----
    hipMemsetAsync(cnt, 0, (size_t)Nn * 4, stream);
    edge_count<<<(E + 255) / 256, 256, 0, stream>>>(ei, cnt, E);
    scan_offsets<<<1, 1024, 0, stream>>>(cnt, offs, cur, Nn);
    fill_edges<<<(E + 255) / 256, 256, 0, stream>>>(ei, cur, elist, E);
    gather_mean<<<Mpad / 4, 256, 0, stream>>>(offs, cnt, elist, Abig, Nn, Mpad);

    // ---- RGCN(rel0)+root as ONE K=1536 GEMM, bf16 out ----
    gemm_bt<<<dim3(H / 128, Mpad / 128), 256, 0, stream>>>(Abig, Wbt, nullptr, out1b, b_rgcn, Mpad, H, 1536, 0);

    // ---- GraphConv projection (segment_sum commutes with matmul) ----
    gemm_bt<<<dim3(1, Mpad / 128), 256, 0, stream>>>(out1b, W2tb, C2, nullptr, nullptr, Mpad, 128, 768, 0);

    // ---- tail: head (64 blocks) + ff1 (2048 blocks) + ff2+head (256 blocks) ----
    enc2_head<<<Bb, 256, 0, stream>>>(opt, offs, cnt, elist, C2, bg,
                                      w_qkv2, b_qkv2, w_o2, b_o2, g2a, bb2a, x21);
    ff1_par<<<R * 8, 256, 0, stream>>>(x21, w_ff2a, bf2a, Hf2);
    ff2_tail<<<R, 256, 0, stream>>>(Hf2, x21, w_ff2b, bf2b, g2b, bb2b,
                                    w_l1, b_l1, w_l2, b_l2, (float*)d_out);
}

// Round 7
// 550.598 us; speedup vs baseline: 1.3091x; 1.0367x over previous
//
#include <hip/hip_runtime.h>

typedef unsigned short u16;
typedef unsigned int u32;
typedef __bf16 bf16x8 __attribute__((ext_vector_type(8)));
typedef float f32x4 __attribute__((ext_vector_type(4)));

__device__ __forceinline__ u16 f2bf(float f) {
    union { float f; u32 u; } v; v.f = f;
    u32 r = v.u + 0x7FFFu + ((v.u >> 16) & 1u);   // RNE
    return (u16)(r >> 16);
}
__device__ __forceinline__ float bf2f(u16 h) {
    union { u32 u; float f; } v; v.u = (u32)h << 16; return v.f;
}

// ---------------------------------------------------------------------------
// bf16 GEMM: C[M,N] = A[M,K] @ Bt[N,K]^T (+bias, optional relu)
// If Cb != null, writes bf16 output there instead of fp32 C.
// 128x128 tile, BK=64, 4 waves, 16x16x32 MFMA, global_load_lds width 16,
// XOR-swizzled LDS (chunk ^= row&7). M%128==0, N%128==0, K%64==0.
// ---------------------------------------------------------------------------
__global__ __launch_bounds__(256) void gemm_bt(
    const u16* __restrict__ A, const u16* __restrict__ Bt,
    float* __restrict__ C, u16* __restrict__ Cb, const float* __restrict__ bias,
    int M, int N, int K, int relu)
{
    __shared__ char lA[128 * 64 * 2];
    __shared__ char lB[128 * 64 * 2];
    const int t = threadIdx.x;
    const int w = t >> 6, l = t & 63;
    const int bn = blockIdx.x, bm = blockIdx.y;
    const int wr = w >> 1, wc = w & 1;

    const int srow = w * 8 + (l >> 3);
    const int scol = ((l & 7) ^ (l >> 3)) << 3;     // pre-swizzled source chunk
    const u16* gA = A + (size_t)(bm * 128 + srow) * K + scol;
    const u16* gB = Bt + (size_t)(bn * 128 + srow) * K + scol;

    f32x4 zero = {0.f, 0.f, 0.f, 0.f};
    f32x4 acc[4][4];
#pragma unroll
    for (int i = 0; i < 4; i++)
#pragma unroll
        for (int j = 0; j < 4; j++) acc[i][j] = zero;

    const int arow = wr * 64 + (l & 15);
    const int brow = wc * 64 + (l & 15);
    const int kx = l >> 4;
    const int sw = l & 7;       // == row&7 for fragment rows

    for (int k0 = 0; k0 < K; k0 += 64) {
#pragma unroll
        for (int c2 = 0; c2 < 4; ++c2) {
            __builtin_amdgcn_global_load_lds(
                (const __attribute__((address_space(1))) void*)(gA + (size_t)c2 * 32 * K + k0),
                (__attribute__((address_space(3))) void*)(lA + c2 * 4096 + w * 1024), 16, 0, 0);
            __builtin_amdgcn_global_load_lds(
                (const __attribute__((address_space(1))) void*)(gB + (size_t)c2 * 32 * K + k0),
                (__attribute__((address_space(3))) void*)(lB + c2 * 4096 + w * 1024), 16, 0, 0);
        }
        __syncthreads();
#pragma unroll
        for (int kk = 0; kk < 2; ++kk) {
            bf16x8 af[4], bfr[4];
#pragma unroll
            for (int mi = 0; mi < 4; ++mi)
                af[mi] = *(const bf16x8*)(lA + (arow + mi * 16) * 128 + (((kk * 4 + kx) ^ sw) << 4));
#pragma unroll
            for (int ni = 0; ni < 4; ++ni)
                bfr[ni] = *(const bf16x8*)(lB + (brow + ni * 16) * 128 + (((kk * 4 + kx) ^ sw) << 4));
#pragma unroll
            for (int mi = 0; mi < 4; ++mi)
#pragma unroll
                for (int ni = 0; ni < 4; ++ni)
                    acc[mi][ni] = __builtin_amdgcn_mfma_f32_16x16x32_bf16(af[mi], bfr[ni], acc[mi][ni], 0, 0, 0);
        }
        __syncthreads();
    }

    const int cm = bm * 128 + wr * 64;
    const int cn = bn * 128 + wc * 64;
#pragma unroll
    for (int mi = 0; mi < 4; ++mi) {
#pragma unroll
        for (int ni = 0; ni < 4; ++ni) {
            int row0 = cm + mi * 16 + (l >> 4) * 4;
            int col = cn + ni * 16 + (l & 15);
            float bv = bias ? bias[col] : 0.f;
#pragma unroll
            for (int r = 0; r < 4; ++r) {
                float v = acc[mi][ni][r] + bv;
                if (relu) v = fmaxf(v, 0.f);
                if (Cb) Cb[(size_t)(row0 + r) * N + col] = f2bf(v);
                else    C [(size_t)(row0 + r) * N + col] = v;
            }
        }
    }
}

// ---------------------------------------------------------------------------
// batched fp32 -> bf16 weight conversion (6 jobs, blockIdx.z selects)
struct CJob { const float* src; u16* dst; long n4; };
struct CJobs6 { CJob j[6]; };
__global__ void conv6_bf16(CJobs6 jobs)
{
    CJob jb = jobs.j[blockIdx.z];
    long i = (long)blockIdx.x * blockDim.x + threadIdx.x;
    long stride = (long)gridDim.x * blockDim.x;
    for (; i < jb.n4; i += stride) {
        float4 v = ((const float4*)jb.src)[i];
        ushort4 o;
        o.x = f2bf(v.x); o.y = f2bf(v.y); o.z = f2bf(v.z); o.w = f2bf(v.w);
        ((ushort4*)jb.dst)[i] = o;
    }
}

// batched transpose fp32 [Rr,Cc] -> bf16 out[c*ldo + r] (2 jobs)
struct TJob { const float* src; u16* dst; int Rr, Cc, ldo; };
struct TJobs2 { TJob j[2]; };
__global__ void transpose2_bf16(TJobs2 jobs)
{
    TJob jb = jobs.j[blockIdx.z];
    __shared__ float tile[32][33];
    int c0 = blockIdx.x * 32, r0 = blockIdx.y * 32;
    if (c0 >= jb.Cc || r0 >= jb.Rr) return;
    int tx = threadIdx.x, ty = threadIdx.y;
    for (int dy = 0; dy < 32; dy += 8) {
        int r = r0 + ty + dy, c = c0 + tx;
        tile[ty + dy][tx] = (r < jb.Rr && c < jb.Cc) ? jb.src[(size_t)r * jb.Cc + c] : 0.f;
    }
    __syncthreads();
    for (int dy = 0; dy < 32; dy += 8) {
        int c = c0 + ty + dy, r = r0 + tx;
        if (c < jb.Cc && r < jb.Rr) jb.dst[(size_t)c * jb.ldo + r] = f2bf(tile[tx][ty + dy]);
    }
}

// bc[n] = sum_k b_rgcn[k] * W2[k,n]  (W2 = [wg_rel | wg_root], 768x128)
__global__ void bc_prep(const float* __restrict__ b_rgcn, const float* __restrict__ wg_rel,
                        const float* __restrict__ wg_root, float* __restrict__ bc)
{
    int n = threadIdx.x;     // 0..127
    const float* W = (n < 64) ? (wg_rel + n) : (wg_root + (n - 64));
    float s = 0.f;
    for (int k = 0; k < 768; k++) s += b_rgcn[k] * W[(size_t)k * 64];
    bc[n] = s;
}

// nodes fp32 [Nn,768] -> bf16 into Abig[Mpad,1536] cols 0:768, pad rows zero
__global__ void conv_nodes_str(const float* __restrict__ nodes, u16* __restrict__ Abig,
                               int Nn, int Mpad)
{
    long i = (long)blockIdx.x * blockDim.x + threadIdx.x;
    long stride = (long)gridDim.x * blockDim.x;
    long n4 = (long)Mpad * 192;     // float4 groups over [Mpad,768]
    for (; i < n4; i += stride) {
        long row = i / 192, c4 = i % 192;
        ushort4 o;
        if ((int)row < Nn) {
            float4 v = ((const float4*)nodes)[i];
            o.x = f2bf(v.x); o.y = f2bf(v.y); o.z = f2bf(v.z); o.w = f2bf(v.w);
        } else { o.x = 0; o.y = 0; o.z = 0; o.w = 0; }
        ((ushort4*)Abig)[row * 384 + c4] = o;
    }
}

__global__ void gather_x0(const float* __restrict__ nodes, const int* __restrict__ opt,
                          float* __restrict__ x0, u16* __restrict__ x0b, int H)
{
    int r = blockIdx.x;
    size_t srcb = (size_t)opt[r] * H;
    for (int c = threadIdx.x; c < H; c += blockDim.x) {
        float v = nodes[srcb + c];
        x0[(size_t)r * H + c] = v;
        x0b[(size_t)r * H + c] = f2bf(v);
    }
}

// x2 fp32 [R,768] -> Abig rows opt[r], cols 0:768 (bf16)
__global__ void scatter_opts_str(const float* __restrict__ x2, const int* __restrict__ opt,
                                 u16* __restrict__ Abig)
{
    int r = blockIdx.x;
    size_t dstb = (size_t)opt[r] * 1536;
    for (int c = threadIdx.x; c < 768; c += blockDim.x)
        Abig[dstb + c] = f2bf(x2[(size_t)r * 768 + c]);
}

// S=4 attention (enc1), bf16 out; one block per (batch,head), wave w = query row
__global__ __launch_bounds__(256) void attn_small_b(
    const float* __restrict__ qkv, u16* __restrict__ out, int H, int nh, int hd)
{
    int b = blockIdx.x / nh, h = blockIdx.x % nh;
    int w = threadIdx.x >> 6, l = threadIdx.x & 63;
    __shared__ float sc[4][4];
    int qs = 3 * H;
    const float* qr = qkv + (size_t)(b * 4 + w) * qs + h * hd;
    float scale = rsqrtf((float)hd);
    for (int sj = 0; sj < 4; ++sj) {
        const float* kr = qkv + (size_t)(b * 4 + sj) * qs + H + h * hd;
        float p = 0.f;
        for (int i = l; i < hd; i += 64) p += qr[i] * kr[i];
        for (int off = 32; off; off >>= 1) p += __shfl_down(p, off, 64);
        if (l == 0) sc[w][sj] = p * scale;
    }
    __syncthreads();
    float a0 = sc[w][0], a1 = sc[w][1], a2 = sc[w][2], a3 = sc[w][3];
    float mx = fmaxf(fmaxf(a0, a1), fmaxf(a2, a3));
    float e0 = __expf(a0 - mx), e1 = __expf(a1 - mx), e2 = __expf(a2 - mx), e3 = __expf(a3 - mx);
    float inv = 1.f / (e0 + e1 + e2 + e3);
    e0 *= inv; e1 *= inv; e2 *= inv; e3 *= inv;
    const float* v0 = qkv + (size_t)(b * 4 + 0) * qs + 2 * H + h * hd;
    const float* v1 = v0 + qs; const float* v2 = v1 + qs; const float* v3 = v2 + qs;
    u16* orow = out + (size_t)(b * 4 + w) * H + h * hd;
    for (int i = l; i < hd; i += 64)
        orow[i] = f2bf(e0 * v0[i] + e1 * v1[i] + e2 * v2[i] + e3 * v3[i]);
}

// LN over 768: out = g*(x+res - m)*rinv + b, optional bf16 copy
__global__ __launch_bounds__(256) void ln768(
    const float* __restrict__ x, const float* __restrict__ res,
    const float* __restrict__ g, const float* __restrict__ be,
    float* __restrict__ out, u16* __restrict__ outb)
{
    int row = blockIdx.x, t = threadIdx.x;
    const float* xr = x + (size_t)row * 768;
    const float* rr = res + (size_t)row * 768;
    float v[3]; float s = 0.f, q = 0.f;
#pragma unroll
    for (int i = 0; i < 3; i++) {
        float a = xr[t + i * 256] + rr[t + i * 256];
        v[i] = a; s += a; q += a * a;
    }
    for (int off = 32; off; off >>= 1) { s += __shfl_down(s, off, 64); q += __shfl_down(q, off, 64); }
    __shared__ float ss[4], qq[4];
    int w = t >> 6, l = t & 63;
    if (l == 0) { ss[w] = s; qq[w] = q; }
    __syncthreads();
    s = ss[0] + ss[1] + ss[2] + ss[3];
    q = qq[0] + qq[1] + qq[2] + qq[3];
    float m = s * (1.f / 768.f);
    float ri = rsqrtf(q * (1.f / 768.f) - m * m + 1e-5f);
#pragma unroll
    for (int i = 0; i < 3; i++) {
        int c = t + i * 256;
        float o = g[c] * (v[i] - m) * ri + be[c];
        out[(size_t)row * 768 + c] = o;
        if (outb) outb[(size_t)row * 768 + c] = f2bf(o);
    }
}

// ---------------------------------------------------------------------------
// CSR build: cnt (atomics) -> exclusive scan (offs, cur) -> bucket fill
__global__ void edge_count(const int* __restrict__ ei, int* __restrict__ cnt, int E)
{
    int e = blockIdx.x * blockDim.x + threadIdx.x;
    if (e < E) atomicAdd(&cnt[ei[E + e]], 1);
}

__global__ __launch_bounds__(1024) void scan_offsets(
    const int* __restrict__ cnt, int* __restrict__ offs, int* __restrict__ cur, int n)
{
    __shared__ int part[1024];
    int t = threadIdx.x;
    int per = (n + 1023) / 1024;
    int base = t * per;
    int local = 0;
    for (int i = 0; i < per; i++) {
        int idx = base + i;
        if (idx < n) local += cnt[idx];
    }
    part[t] = local;
    __syncthreads();
    for (int off = 1; off < 1024; off <<= 1) {
        int v = (t >= off) ? part[t - off] : 0;
        __syncthreads();
        part[t] += v;
        __syncthreads();
    }
    int prefix = (t == 0) ? 0 : part[t - 1];
    for (int i = 0; i < per; i++) {
        int idx = base + i;
        if (idx < n) {
            offs[idx] = prefix;
            cur[idx] = prefix;
            prefix += cnt[idx];
        }
    }
}

__global__ void fill_edges(const int* __restrict__ ei, int* __restrict__ cur,
                           int* __restrict__ elist, int E)
{
    int e = blockIdx.x * blockDim.x + threadIdx.x;
    if (e < E) {
        int d = ei[E + e];
        int pos = atomicAdd(&cur[d], 1);
        elist[pos] = ei[e];    // src
    }
}

// aggN[d] = mean over in-edges of nodes2[src]; writes Abig cols 768:1536 (bf16).
// Coalesced: lane l, pass j4 covers ushort4 index j4*64+l (512B contiguous/pass).
__global__ __launch_bounds__(256) void gather_mean(
    const int* __restrict__ offs, const int* __restrict__ cnt, const int* __restrict__ elist,
    u16* Abig, int Nn, int Mpad)
{
    int w = threadIdx.x >> 6, l = threadIdx.x & 63;
    int d = blockIdx.x * 4 + w;
    if (d >= Mpad) return;
    float acc[12];
#pragma unroll
    for (int j = 0; j < 12; j++) acc[j] = 0.f;
    float inv = 0.f;
    if (d < Nn) {
        int base = offs[d], c = cnt[d];
        for (int i = 0; i < c; i++) {
            int s = elist[base + i];
            const ushort4* p = (const ushort4*)(Abig + (size_t)s * 1536);
#pragma unroll
            for (int j4 = 0; j4 < 3; j4++) {
                ushort4 v = p[j4 * 64 + l];
                acc[j4 * 4 + 0] += bf2f(v.x);
                acc[j4 * 4 + 1] += bf2f(v.y);
                acc[j4 * 4 + 2] += bf2f(v.z);
                acc[j4 * 4 + 3] += bf2f(v.w);
            }
        }
        inv = 1.f / (float)max(c, 1);
    }
    ushort4* q = (ushort4*)(Abig + (size_t)d * 1536 + 768);
#pragma unroll
    for (int j4 = 0; j4 < 3; j4++) {
        ushort4 o;
        o.x = f2bf(acc[j4 * 4 + 0] * inv);
        o.y = f2bf(acc[j4 * 4 + 1] * inv);
        o.z = f2bf(acc[j4 * 4 + 2] * inv);
        o.w = f2bf(acc[j4 * 4 + 3] * inv);
        q[j4 * 64 + l] = o;
    }
}

// ---------------------------------------------------------------------------
// enc2_head: out2 readout + qkv + attn + o-proj + LN(g2a) -> x21 [256,64]
__global__ __launch_bounds__(256) void enc2_head(
    const int* __restrict__ opt, const int* __restrict__ offs, const int* __restrict__ cnt,
    const int* __restrict__ elist, const float* __restrict__ C2, const float* __restrict__ bg,
    const float* __restrict__ w_qkv2, const float* __restrict__ b_qkv2,
    const float* __restrict__ w_o2, const float* __restrict__ b_o2,
    const float* __restrict__ g2a, const float* __restrict__ bb2a,
    float* __restrict__ x21)
{
    __shared__ float X[4][64];
    __shared__ float QKV[4][192];
    __shared__ float T[4][64];
    int b = blockIdx.x;
    int w = threadIdx.x >> 6, l = threadIdx.x & 63;
    int row = b * 4 + w;

    // GraphConv readout at option node: sum_in C2rel[src] + bg + C2root[d]
    {
        int d = opt[row];
        float acc = bg[l] + C2[(size_t)d * 128 + 64 + l];
        int base = offs[d], c = cnt[d];
        for (int i = 0; i < c; i++) {
            int s = elist[base + i];
            acc += C2[(size_t)s * 128 + l];
        }
        X[w][l] = acc;
    }
    __syncthreads();

    // qkv (192 outs/row, 3 per lane)
#pragma unroll
    for (int j = 0; j < 3; j++) {
        int n = l + j * 64;
        const float* wr = w_qkv2 + (size_t)n * 64;
        float s = b_qkv2[n];
        for (int k = 0; k < 64; k++) s += X[w][k] * wr[k];
        QKV[w][n] = s;
    }
    __syncthreads();

    // attention (nh=2, hd=32): lane l -> head l>>5
    {
        float q = QKV[w][l];
        float p0 = q * QKV[0][64 + l], p1 = q * QKV[1][64 + l];
        float p2 = q * QKV[2][64 + l], p3 = q * QKV[3][64 + l];
#pragma unroll
        for (int off = 1; off < 32; off <<= 1) {
            p0 += __shfl_xor(p0, off, 64); p1 += __shfl_xor(p1, off, 64);
            p2 += __shfl_xor(p2, off, 64); p3 += __shfl_xor(p3, off, 64);
        }
        p0 *= 0.1767766953f; p1 *= 0.1767766953f; p2 *= 0.1767766953f; p3 *= 0.1767766953f;
        float mx = fmaxf(fmaxf(p0, p1), fmaxf(p2, p3));
        float e0 = __expf(p0 - mx), e1 = __expf(p1 - mx), e2 = __expf(p2 - mx), e3 = __expf(p3 - mx);
        float inv = 1.f / (e0 + e1 + e2 + e3);
        T[w][l] = (e0 * QKV[0][128 + l] + e1 * QKV[1][128 + l] +
                   e2 * QKV[2][128 + l] + e3 * QKV[3][128 + l]) * inv;
    }
    __syncthreads();

    // o-proj + residual + LN (g2a)
    {
        const float* wr = w_o2 + (size_t)l * 64;
        float s = b_o2[l];
        for (int k = 0; k < 64; k++) s += T[w][k] * wr[k];
        float xa = s + X[w][l];
        float sum = xa, sq = xa * xa;
#pragma unroll
        for (int off = 1; off < 64; off <<= 1) {
            sum += __shfl_xor(sum, off, 64);
            sq  += __shfl_xor(sq, off, 64);
        }
        float m = sum * (1.f / 64.f);
        float ri = rsqrtf(sq * (1.f / 64.f) - m * m + 1e-5f);
        x21[(size_t)row * 64 + l] = g2a[l] * (xa - m) * ri + bb2a[l];
    }
}

// ff1: Hf[r,n] = relu(x21[r,:]·wf1[n,:] + bf1[n]); one output per thread.
__global__ __launch_bounds__(256) void ff1_par(
    const float* __restrict__ x21, const float* __restrict__ wf1,
    const float* __restrict__ bf1, float* __restrict__ Hf)
{
    __shared__ float X[64];
    int b = blockIdx.x, t = threadIdx.x;
    int r = b >> 3, n = (b & 7) * 256 + t;
    if (t < 64) X[t] = x21[(size_t)r * 64 + t];
    __syncthreads();
    const float4* wr4 = (const float4*)(wf1 + (size_t)n * 64);
    float s = bf1[n];
#pragma unroll
    for (int k4 = 0; k4 < 16; k4++) {
        float4 wv = wr4[k4];
        const float* xp = X + k4 * 4;
        s += wv.x * xp[0] + wv.y * xp[1] + wv.z * xp[2] + wv.w * xp[3];
    }
    Hf[(size_t)r * 2048 + n] = fmaxf(s, 0.f);
}

// ff2 + residual + LN(g2b) + l1 + tanh + l2. One block per row, 4 waves.
__global__ __launch_bounds__(256) void ff2_tail(
    const float* __restrict__ Hf, const float* __restrict__ x21,
    const float* __restrict__ wf2, const float* __restrict__ bf2,
    const float* __restrict__ g2b, const float* __restrict__ bb2b,
    const float* __restrict__ w_l1, const float* __restrict__ b_l1,
    const float* __restrict__ w_l2, const float* __restrict__ b_l2,
    float* __restrict__ out)
{
    __shared__ float HL[2048];
    __shared__ float part[4][64];
    __shared__ float X2[64];
    int r = blockIdx.x, t = threadIdx.x;
    int w = t >> 6, l = t & 63;

    {
        const float4* src = (const float4*)(Hf + (size_t)r * 2048);
        float4* dst = (float4*)HL;
        dst[t] = src[t];
        dst[t + 256] = src[t + 256];
    }
    __syncthreads();

    {
        const float4* wr4 = (const float4*)(wf2 + (size_t)l * 2048 + w * 512);
        const float* hp = HL + w * 512;
        float s = 0.f;
#pragma unroll 16
        for (int k4 = 0; k4 < 128; k4++) {
            float4 wv = wr4[k4];
            const float* xp = hp + k4 * 4;
            s += wv.x * xp[0] + wv.y * xp[1] + wv.z * xp[2] + wv.w * xp[3];
        }
        part[w][l] = s;
    }
    __syncthreads();

    if (w == 0) {
        float xa = part[0][l] + part[1][l] + part[2][l] + part[3][l] + bf2[l]
                 + x21[(size_t)r * 64 + l];
        float sum = xa, sq = xa * xa;
#pragma unroll
        for (int off = 1; off < 64; off <<= 1) {
            sum += __shfl_xor(sum, off, 64);
            sq  += __shfl_xor(sq, off, 64);
        }
        float m = sum * (1.f / 64.f);
        float ri = rsqrtf(sq * (1.f / 64.f) - m * m + 1e-5f);
        X2[l] = g2b[l] * (xa - m) * ri + bb2b[l];
        __builtin_amdgcn_wave_barrier();
        const float* wr = w_l1 + (size_t)l * 64;
        float s = b_l1[l];
        for (int k = 0; k < 64; k++) s += X2[k] * wr[k];
        float tv = tanhf(s);
        float p = tv * w_l2[l];
#pragma unroll
        for (int off = 1; off < 64; off <<= 1) p += __shfl_xor(p, off, 64);
        if (l == 0) out[r] = p + b_l2[0];
    }
}

// ---------------------------------------------------------------------------
extern "C" void kernel_launch(void* const* d_in, const int* in_sizes, int n_in,
                              void* d_out, int out_size, void* d_ws, size_t ws_size,
                              hipStream_t stream)
{
    const float* nodes  = (const float*)d_in[0];
    const int*   ei     = (const int*)d_in[1];
    const int*   opt    = (const int*)d_in[2];
    const float* w_qkv1 = (const float*)d_in[3];
    const float* b_qkv1 = (const float*)d_in[4];
    const float* w_o1   = (const float*)d_in[5];
    const float* b_o1   = (const float*)d_in[6];
    const float* g1a    = (const float*)d_in[7];
    const float* bb1a   = (const float*)d_in[8];
    const float* w_ff1a = (const float*)d_in[9];
    const float* bf1a   = (const float*)d_in[10];
    const float* w_ff1b = (const float*)d_in[11];
    const float* bf1b   = (const float*)d_in[12];
    const float* g1b    = (const float*)d_in[13];
    const float* bb1b   = (const float*)d_in[14];
    // d_in[15..28]: wq..b6 — dead code (edge_type ≡ 0: softmax over singleton axis)
    const float* w_rel  = (const float*)d_in[29];
    const float* w_root = (const float*)d_in[30];
    const float* b_rgcn = (const float*)d_in[31];
    const float* wg_rel = (const float*)d_in[32];
    const float* wg_root= (const float*)d_in[33];
    const float* bg     = (const float*)d_in[34];
    const float* w_qkv2 = (const float*)d_in[35];
    const float* b_qkv2 = (const float*)d_in[36];
    const float* w_o2   = (const float*)d_in[37];
    const float* b_o2   = (const float*)d_in[38];
    const float* g2a    = (const float*)d_in[39];
    const float* bb2a   = (const float*)d_in[40];
    const float* w_ff2a = (const float*)d_in[41];
    const float* bf2a   = (const float*)d_in[42];
    const float* w_ff2b = (const float*)d_in[43];
    const float* bf2b   = (const float*)d_in[44];
    const float* g2b    = (const float*)d_in[45];
    const float* bb2b   = (const float*)d_in[46];
    const float* w_l1   = (const float*)d_in[47];
    const float* b_l1   = (const float*)d_in[48];
    const float* w_l2   = (const float*)d_in[49];
    const float* b_l2   = (const float*)d_in[50];

    const int H = 768, F = 2048;
    const int Nn = in_sizes[0] / H;            // 20000
    const int E  = in_sizes[1] / 2;            // 40000
    const int R  = in_sizes[2];                // 256 option rows
    const int Mpad = (Nn + 127) & ~127;        // 20096
    const int Bb = R / 4;                      // 64 batches

    char* ws = (char*)d_ws;
    size_t off = 0;
    auto alloc = [&](size_t b) -> char* {
        char* p = ws + off; off += (b + 255) & ~(size_t)255; return p;
    };
    // bf16 weights
    u16* wqkv1b  = (u16*)alloc((size_t)3 * H * H * 2);
    u16* wo1b    = (u16*)alloc((size_t)H * H * 2);
    u16* wff1ab  = (u16*)alloc((size_t)F * H * 2);
    u16* wff1bb  = (u16*)alloc((size_t)H * F * 2);
    u16* Wbraw   = (u16*)alloc((size_t)1536 * H * 2);     // [w_root ; w_rel0] row-major bf16
    u16* W2tb    = (u16*)alloc((size_t)128 * H * 2);      // [wg_rel^T ; wg_root^T]
    u16* WcT     = (u16*)alloc((size_t)128 * 1536 * 2);   // (Wb @ W2)^T  bf16
    float* bc    = (float*)alloc((size_t)128 * 4);        // b_rgcn @ W2
    // encoder1 activations
    float* x0   = (float*)alloc((size_t)R * H * 4);
    u16*  x0b   = (u16*)alloc((size_t)R * H * 2);
    float* qkvb = (float*)alloc((size_t)R * 3 * H * 4);
    u16*  atnob = (u16*)alloc((size_t)R * H * 2);
    float* obuf = (float*)alloc((size_t)R * H * 4);
    float* x1   = (float*)alloc((size_t)R * H * 4);
    u16*  x1b   = (u16*)alloc((size_t)R * H * 2);
    u16*  ffhb  = (u16*)alloc((size_t)R * F * 2);
    float* ffo  = (float*)alloc((size_t)R * H * 4);
    float* x2   = (float*)alloc((size_t)R * H * 4);
    // big buffers
    u16*  Abig  = (u16*)alloc((size_t)Mpad * 1536 * 2);   // [nodes2 | aggN] bf16
    float* C2   = (float*)alloc((size_t)Mpad * 128 * 4);
    // CSR
    int* cnt   = (int*)alloc((size_t)Nn * 4);
    int* offs  = (int*)alloc((size_t)Nn * 4);
    int* cur   = (int*)alloc((size_t)Nn * 4);
    int* elist = (int*)alloc((size_t)E * 4);
    // tail
    float* x21 = (float*)alloc((size_t)R * 64 * 4);
    float* Hf2 = (float*)alloc((size_t)R * F * 4);
    (void)ws_size; (void)n_in; (void)out_size;

    // ---- weight prep ----
    {
        CJobs6 cj;
        cj.j[0] = { w_qkv1, wqkv1b, (long)3 * H * H / 4 };
        cj.j[1] = { w_o1,   wo1b,   (long)H * H / 4 };
        cj.j[2] = { w_ff1a, wff1ab, (long)F * H / 4 };
        cj.j[3] = { w_ff1b, wff1bb, (long)H * F / 4 };
        cj.j[4] = { w_root, Wbraw,                    (long)H * H / 4 };
        cj.j[5] = { w_rel,  Wbraw + (size_t)H * H,    (long)H * H / 4 };   // w_rel[0] only
        conv6_bf16<<<dim3(432, 1, 6), 256, 0, stream>>>(cj);
        TJobs2 tj;
        tj.j[0] = { wg_rel,  W2tb,                    768, 64, 768 };
        tj.j[1] = { wg_root, W2tb + (size_t)64 * 768, 768, 64, 768 };
        transpose2_bf16<<<dim3(2, 24, 2), dim3(32, 8), 0, stream>>>(tj);
    }
    // WcT[128,1536] = W2tb[128,768] @ Wbraw[1536,768]^T  (i.e. (Wb@W2)^T)
    gemm_bt<<<dim3(1536 / 128, 1), 256, 0, stream>>>(W2tb, Wbraw, nullptr, WcT, nullptr, 128, 1536, 768, 0);
    bc_prep<<<1, 128, 0, stream>>>(b_rgcn, wg_rel, wg_root, bc);

    // ---- encoder layer 1 on option nodes (256 x 768) ----
    gather_x0<<<R, 256, 0, stream>>>(nodes, opt, x0, x0b, H);
    gemm_bt<<<dim3(3 * H / 128, R / 128), 256, 0, stream>>>(x0b, wqkv1b, qkvb, nullptr, b_qkv1, R, 3 * H, H, 0);
    attn_small_b<<<Bb * 2, 256, 0, stream>>>(qkvb, atnob, H, 2, H / 2);
    gemm_bt<<<dim3(H / 128, R / 128), 256, 0, stream>>>(atnob, wo1b, obuf, nullptr, b_o1, R, H, H, 0);
    ln768<<<R, 256, 0, stream>>>(obuf, x0, g1a, bb1a, x1, x1b);
    gemm_bt<<<dim3(F / 128, R / 128), 256, 0, stream>>>(x1b, wff1ab, nullptr, ffhb, bf1a, R, F, H, 1);
    gemm_bt<<<dim3(H / 128, R / 128), 256, 0, stream>>>(ffhb, wff1bb, ffo, nullptr, bf1b, R, H, F, 0);
    ln768<<<R, 256, 0, stream>>>(ffo, x1, g1b, bb1b, x2, nullptr);

    // ---- nodes2 into Abig cols 0:768 (bf16, padded) ----
    conv_nodes_str<<<2048, 256, 0, stream>>>(nodes, Abig, Nn, Mpad);
    scatter_opts_str<<<R, 256, 0, stream>>>(x2, opt, Abig);

    // ---- CSR build + mean-aggregate nodes2 into Abig cols 768:1536 ----
    hipMemsetAsync(cnt, 0, (size_t)Nn * 4, stream);
    edge_count<<<(E + 255) / 256, 256, 0, stream>>>(ei, cnt, E);
    scan_offsets<<<1, 1024, 0, stream>>>(cnt, offs, cur, Nn);
    fill_edges<<<(E + 255) / 256, 256, 0, stream>>>(ei, cur, elist, E);
    gather_mean<<<Mpad / 4, 256, 0, stream>>>(offs, cnt, elist, Abig, Nn, Mpad);

    // ---- fused RGCN+GraphConv projection: C2 = Abig @ Wc + bc ----
    // (out1 eliminated: C2 = (Abig@Wb + 1·b_rgcn)@W2 = Abig@(Wb@W2) + 1·(b_rgcn@W2))
    gemm_bt<<<dim3(1, Mpad / 128), 256, 0, stream>>>(Abig, WcT, C2, nullptr, bc, Mpad, 128, 1536, 0);

    // ---- tail: head (64 blocks) + ff1 (2048 blocks) + ff2+head (256 blocks) ----
    enc2_head<<<Bb, 256, 0, stream>>>(opt, offs, cnt, elist, C2, bg,
                                      w_qkv2, b_qkv2, w_o2, b_o2, g2a, bb2a, x21);
    ff1_par<<<R * 8, 256, 0, stream>>>(x21, w_ff2a, bf2a, Hf2);
    ff2_tail<<<R, 256, 0, stream>>>(Hf2, x21, w_ff2b, bf2b, g2b, bb2b,
                                    w_l1, b_l1, w_l2, b_l2, (float*)d_out);
}

// Round 9
// 476.140 us; speedup vs baseline: 1.5138x; 1.1564x over previous
//
#include <hip/hip_runtime.h>

typedef unsigned short u16;
typedef unsigned int u32;
typedef __bf16 bf16x8 __attribute__((ext_vector_type(8)));
typedef float f32x4 __attribute__((ext_vector_type(4)));

__device__ __forceinline__ u16 f2bf(float f) {
    union { float f; u32 u; } v; v.f = f;
    u32 r = v.u + 0x7FFFu + ((v.u >> 16) & 1u);   // RNE
    return (u16)(r >> 16);
}
__device__ __forceinline__ float bf2f(u16 h) {
    union { u32 u; float f; } v; v.u = (u32)h << 16; return v.f;
}

// ---------------------------------------------------------------------------
// bf16 GEMM: C[M,N] = A[M,K] @ Bt[N,K]^T (+bias). fp32 or bf16 out.
// 128x128 tile, BK=64, 4 waves, 16x16x32 MFMA, global_load_lds width 16,
// XOR-swizzled LDS. M%128==0, N%128==0, K%64==0.
// ---------------------------------------------------------------------------
__global__ __launch_bounds__(256) void gemm_bt(
    const u16* __restrict__ A, const u16* __restrict__ Bt,
    float* __restrict__ C, u16* __restrict__ Cb, const float* __restrict__ bias,
    int M, int N, int K, int relu)
{
    __shared__ char lA[128 * 64 * 2];
    __shared__ char lB[128 * 64 * 2];
    const int t = threadIdx.x;
    const int w = t >> 6, l = t & 63;
    const int bn = blockIdx.x, bm = blockIdx.y;
    const int wr = w >> 1, wc = w & 1;

    const int srow = w * 8 + (l >> 3);
    const int scol = ((l & 7) ^ (l >> 3)) << 3;
    const u16* gA = A + (size_t)(bm * 128 + srow) * K + scol;
    const u16* gB = Bt + (size_t)(bn * 128 + srow) * K + scol;

    f32x4 zero = {0.f, 0.f, 0.f, 0.f};
    f32x4 acc[4][4];
#pragma unroll
    for (int i = 0; i < 4; i++)
#pragma unroll
        for (int j = 0; j < 4; j++) acc[i][j] = zero;

    const int arow = wr * 64 + (l & 15);
    const int brow = wc * 64 + (l & 15);
    const int kx = l >> 4;
    const int sw = l & 7;

    for (int k0 = 0; k0 < K; k0 += 64) {
#pragma unroll
        for (int c2 = 0; c2 < 4; ++c2) {
            __builtin_amdgcn_global_load_lds(
                (const __attribute__((address_space(1))) void*)(gA + (size_t)c2 * 32 * K + k0),
                (__attribute__((address_space(3))) void*)(lA + c2 * 4096 + w * 1024), 16, 0, 0);
            __builtin_amdgcn_global_load_lds(
                (const __attribute__((address_space(1))) void*)(gB + (size_t)c2 * 32 * K + k0),
                (__attribute__((address_space(3))) void*)(lB + c2 * 4096 + w * 1024), 16, 0, 0);
        }
        __syncthreads();
#pragma unroll
        for (int kk = 0; kk < 2; ++kk) {
            bf16x8 af[4], bfr[4];
#pragma unroll
            for (int mi = 0; mi < 4; ++mi)
                af[mi] = *(const bf16x8*)(lA + (arow + mi * 16) * 128 + (((kk * 4 + kx) ^ sw) << 4));
#pragma unroll
            for (int ni = 0; ni < 4; ++ni)
                bfr[ni] = *(const bf16x8*)(lB + (brow + ni * 16) * 128 + (((kk * 4 + kx) ^ sw) << 4));
#pragma unroll
            for (int mi = 0; mi < 4; ++mi)
#pragma unroll
                for (int ni = 0; ni < 4; ++ni)
                    acc[mi][ni] = __builtin_amdgcn_mfma_f32_16x16x32_bf16(af[mi], bfr[ni], acc[mi][ni], 0, 0, 0);
        }
        __syncthreads();
    }

    const int cm = bm * 128 + wr * 64;
    const int cn = bn * 128 + wc * 64;
#pragma unroll
    for (int mi = 0; mi < 4; ++mi) {
#pragma unroll
        for (int ni = 0; ni < 4; ++ni) {
            int row0 = cm + mi * 16 + (l >> 4) * 4;
            int col = cn + ni * 16 + (l & 15);
            float bv = bias ? bias[col] : 0.f;
#pragma unroll
            for (int r = 0; r < 4; ++r) {
                float v = acc[mi][ni][r] + bv;
                if (relu) v = fmaxf(v, 0.f);
                if (Cb) Cb[(size_t)(row0 + r) * N + col] = f2bf(v);
                else    C [(size_t)(row0 + r) * N + col] = v;
            }
        }
    }
}

// ---------------------------------------------------------------------------
// Split-K bf16 GEMM: P[ks][M][N] partial = A[:, ks*Kc:(ks+1)*Kc] @ Bt^T slice.
// grid (N/128, M/128, KS). No bias/act (reducers handle epilogues).
// Fixes the latency-bound small-M GEMMs (round-7: 12 blocks, occ 0.45%).
// ---------------------------------------------------------------------------
__global__ __launch_bounds__(256) void gemm_bt_sk(
    const u16* __restrict__ A, const u16* __restrict__ Bt,
    float* __restrict__ P, int M, int N, int K, int Kc)
{
    __shared__ char lA[128 * 64 * 2];
    __shared__ char lB[128 * 64 * 2];
    const int t = threadIdx.x;
    const int w = t >> 6, l = t & 63;
    const int bn = blockIdx.x, bm = blockIdx.y, ks = blockIdx.z;
    const int wr = w >> 1, wc = w & 1;

    const int srow = w * 8 + (l >> 3);
    const int scol = ((l & 7) ^ (l >> 3)) << 3;
    const u16* gA = A + (size_t)(bm * 128 + srow) * K + scol;
    const u16* gB = Bt + (size_t)(bn * 128 + srow) * K + scol;

    f32x4 zero = {0.f, 0.f, 0.f, 0.f};
    f32x4 acc[4][4];
#pragma unroll
    for (int i = 0; i < 4; i++)
#pragma unroll
        for (int j = 0; j < 4; j++) acc[i][j] = zero;

    const int arow = wr * 64 + (l & 15);
    const int brow = wc * 64 + (l & 15);
    const int kx = l >> 4;
    const int sw = l & 7;

    const int kbeg = ks * Kc, kend = kbeg + Kc;
    for (int k0 = kbeg; k0 < kend; k0 += 64) {
#pragma unroll
        for (int c2 = 0; c2 < 4; ++c2) {
            __builtin_amdgcn_global_load_lds(
                (const __attribute__((address_space(1))) void*)(gA + (size_t)c2 * 32 * K + k0),
                (__attribute__((address_space(3))) void*)(lA + c2 * 4096 + w * 1024), 16, 0, 0);
            __builtin_amdgcn_global_load_lds(
                (const __attribute__((address_space(1))) void*)(gB + (size_t)c2 * 32 * K + k0),
                (__attribute__((address_space(3))) void*)(lB + c2 * 4096 + w * 1024), 16, 0, 0);
        }
        __syncthreads();
#pragma unroll
        for (int kk = 0; kk < 2; ++kk) {
            bf16x8 af[4], bfr[4];
#pragma unroll
            for (int mi = 0; mi < 4; ++mi)
                af[mi] = *(const bf16x8*)(lA + (arow + mi * 16) * 128 + (((kk * 4 + kx) ^ sw) << 4));
#pragma unroll
            for (int ni = 0; ni < 4; ++ni)
                bfr[ni] = *(const bf16x8*)(lB + (brow + ni * 16) * 128 + (((kk * 4 + kx) ^ sw) << 4));
#pragma unroll
            for (int mi = 0; mi < 4; ++mi)
#pragma unroll
                for (int ni = 0; ni < 4; ++ni)
                    acc[mi][ni] = __builtin_amdgcn_mfma_f32_16x16x32_bf16(af[mi], bfr[ni], acc[mi][ni], 0, 0, 0);
        }
        __syncthreads();
    }

    float* Pp = P + (size_t)ks * M * N;
    const int cm = bm * 128 + wr * 64;
    const int cn = bn * 128 + wc * 64;
#pragma unroll
    for (int mi = 0; mi < 4; ++mi) {
#pragma unroll
        for (int ni = 0; ni < 4; ++ni) {
            int row0 = cm + mi * 16 + (l >> 4) * 4;
            int col = cn + ni * 16 + (l & 15);
#pragma unroll
            for (int r = 0; r < 4; ++r)
                Pp[(size_t)(row0 + r) * N + col] = acc[mi][ni][r];
        }
    }
}

// sum KS partials + bias, optional relu, write bf16 (elementwise, grid-stride)
__global__ void sk_reduce_b(const float* __restrict__ P, int KS, long MN, int N,
                            const float* __restrict__ bias, int relu, u16* __restrict__ outb)
{
    long i = (long)blockIdx.x * blockDim.x + threadIdx.x;
    long stride = (long)gridDim.x * blockDim.x;
    for (; i < MN; i += stride) {
        float v = bias ? bias[i % N] : 0.f;
        for (int ks = 0; ks < KS; ks++) v += P[(size_t)ks * MN + i];
        if (relu) v = fmaxf(v, 0.f);
        outb[i] = f2bf(v);
    }
}

// ---------------------------------------------------------------------------
// batched fp32 -> bf16 weight conversion (6 jobs, blockIdx.z selects)
struct CJob { const float* src; u16* dst; long n4; };
struct CJobs6 { CJob j[6]; };
__global__ void conv6_bf16(CJobs6 jobs)
{
    CJob jb = jobs.j[blockIdx.z];
    long i = (long)blockIdx.x * blockDim.x + threadIdx.x;
    long stride = (long)gridDim.x * blockDim.x;
    for (; i < jb.n4; i += stride) {
        float4 v = ((const float4*)jb.src)[i];
        ushort4 o;
        o.x = f2bf(v.x); o.y = f2bf(v.y); o.z = f2bf(v.z); o.w = f2bf(v.w);
        ((ushort4*)jb.dst)[i] = o;
    }
}

// batched transpose fp32 [Rr,Cc] -> bf16 out[c*ldo + r] (2 jobs)
struct TJob { const float* src; u16* dst; int Rr, Cc, ldo; };
struct TJobs2 { TJob j[2]; };
__global__ void transpose2_bf16(TJobs2 jobs)
{
    TJob jb = jobs.j[blockIdx.z];
    __shared__ float tile[32][33];
    int c0 = blockIdx.x * 32, r0 = blockIdx.y * 32;
    if (c0 >= jb.Cc || r0 >= jb.Rr) return;
    int tx = threadIdx.x, ty = threadIdx.y;
    for (int dy = 0; dy < 32; dy += 8) {
        int r = r0 + ty + dy, c = c0 + tx;
        tile[ty + dy][tx] = (r < jb.Rr && c < jb.Cc) ? jb.src[(size_t)r * jb.Cc + c] : 0.f;
    }
    __syncthreads();
    for (int dy = 0; dy < 32; dy += 8) {
        int c = c0 + ty + dy, r = r0 + tx;
        if (c < jb.Cc && r < jb.Rr) jb.dst[(size_t)c * jb.ldo + r] = f2bf(tile[tx][ty + dy]);
    }
}

// bc[n] = sum_k b_rgcn[k] * W2[k,n]  (W2 = [wg_rel | wg_root], 768x128)
__global__ void bc_prep(const float* __restrict__ b_rgcn, const float* __restrict__ wg_rel,
                        const float* __restrict__ wg_root, float* __restrict__ bc)
{
    int n = threadIdx.x;     // 0..127
    const float* W = (n < 64) ? (wg_rel + n) : (wg_root + (n - 64));
    float s = 0.f;
    for (int k = 0; k < 768; k++) s += b_rgcn[k] * W[(size_t)k * 64];
    bc[n] = s;
}

// nodes fp32 [Nn,768] -> bf16 into Abig[Mpad,1536] cols 0:768, pad rows zero
__global__ void conv_nodes_str(const float* __restrict__ nodes, u16* __restrict__ Abig,
                               int Nn, int Mpad)
{
    long i = (long)blockIdx.x * blockDim.x + threadIdx.x;
    long stride = (long)gridDim.x * blockDim.x;
    long n4 = (long)Mpad * 192;
    for (; i < n4; i += stride) {
        long row = i / 192, c4 = i % 192;
        ushort4 o;
        if ((int)row < Nn) {
            float4 v = ((const float4*)nodes)[i];
            o.x = f2bf(v.x); o.y = f2bf(v.y); o.z = f2bf(v.z); o.w = f2bf(v.w);
        } else { o.x = 0; o.y = 0; o.z = 0; o.w = 0; }
        ((ushort4*)Abig)[row * 384 + c4] = o;
    }
}

__global__ void gather_x0(const float* __restrict__ nodes, const int* __restrict__ opt,
                          float* __restrict__ x0, u16* __restrict__ x0b, int H)
{
    int r = blockIdx.x;
    size_t srcb = (size_t)opt[r] * H;
    for (int c = threadIdx.x; c < H; c += blockDim.x) {
        float v = nodes[srcb + c];
        x0[(size_t)r * H + c] = v;
        x0b[(size_t)r * H + c] = f2bf(v);
    }
}

// ---------------------------------------------------------------------------
// attn_fused: consumes qkv split-K partials directly (each (b,h) block owns
// disjoint head slices). Reduce + bias inline, S=4 attention, bf16 out.
// Pq[ks][256][2304]; block = (b,h); wave w = query row w. hd=384, nh=2.
__global__ __launch_bounds__(256) void attn_fused(
    const float* __restrict__ Pq, int KS, const float* __restrict__ b_qkv1,
    u16* __restrict__ atnob)
{
    __shared__ float Q[4][384], Kk[4][384], V[4][384];
    int b = blockIdx.x >> 1, h = blockIdx.x & 1;
    int w = threadIdx.x >> 6, l = threadIdx.x & 63;
    int row = b * 4 + w;
    const int hb = h * 384;
#pragma unroll
    for (int j = 0; j < 6; j++) {
        int c = hb + j * 64 + l;
        float q = b_qkv1[c], k = b_qkv1[768 + c], v = b_qkv1[1536 + c];
        for (int ks = 0; ks < KS; ks++) {
            const float* Pr = Pq + (size_t)ks * 256 * 2304 + (size_t)row * 2304;
            q += Pr[c]; k += Pr[768 + c]; v += Pr[1536 + c];
        }
        Q[w][j * 64 + l] = q; Kk[w][j * 64 + l] = k; V[w][j * 64 + l] = v;
    }
    __syncthreads();
    float sc[4];
#pragma unroll
    for (int sj = 0; sj < 4; sj++) {
        float p = 0.f;
#pragma unroll
        for (int j = 0; j < 6; j++) p += Q[w][j * 64 + l] * Kk[sj][j * 64 + l];
        for (int off = 32; off; off >>= 1) p += __shfl_down(p, off, 64);
        sc[sj] = __shfl(p, 0, 64) * 0.05103103630798287f;   // 1/sqrt(384)
    }
    float mx = fmaxf(fmaxf(sc[0], sc[1]), fmaxf(sc[2], sc[3]));
    float e0 = __expf(sc[0] - mx), e1 = __expf(sc[1] - mx);
    float e2 = __expf(sc[2] - mx), e3 = __expf(sc[3] - mx);
    float inv = 1.f / (e0 + e1 + e2 + e3);
    e0 *= inv; e1 *= inv; e2 *= inv; e3 *= inv;
#pragma unroll
    for (int j = 0; j < 6; j++) {
        int c = j * 64 + l;
        float o = e0 * V[0][c] + e1 * V[1][c] + e2 * V[2][c] + e3 * V[3][c];
        atnob[(size_t)row * 768 + hb + c] = f2bf(o);
    }
}

// ln_reduce768: sum KS partials (N=768) + bias + residual -> LN -> fp32/bf16.
// If opt != null, bf16 output goes to outb[opt[r]*ldo + c] (direct Abig write).
__global__ __launch_bounds__(256) void ln_reduce768(
    const float* __restrict__ P, int KS, const float* __restrict__ bias,
    const float* __restrict__ res, const float* __restrict__ g, const float* __restrict__ be,
    float* __restrict__ outf, u16* __restrict__ outb, const int* __restrict__ opt, int ldo)
{
    int r = blockIdx.x, t = threadIdx.x;
    float v[3]; float s = 0.f, q = 0.f;
#pragma unroll
    for (int i = 0; i < 3; i++) {
        int c = t + i * 256;
        float a = bias[c] + res[(size_t)r * 768 + c];
        for (int ks = 0; ks < KS; ks++) a += P[(size_t)ks * 256 * 768 + (size_t)r * 768 + c];
        v[i] = a; s += a; q += a * a;
    }
    for (int off = 32; off; off >>= 1) { s += __shfl_down(s, off, 64); q += __shfl_down(q, off, 64); }
    __shared__ float ss[4], qq[4];
    int w = t >> 6, l = t & 63;
    if (l == 0) { ss[w] = s; qq[w] = q; }
    __syncthreads();
    s = ss[0] + ss[1] + ss[2] + ss[3];
    q = qq[0] + qq[1] + qq[2] + qq[3];
    float m = s * (1.f / 768.f);
    float ri = rsqrtf(q * (1.f / 768.f) - m * m + 1e-5f);
    size_t ob = opt ? (size_t)opt[r] * ldo : (size_t)r * ldo;
#pragma unroll
    for (int i = 0; i < 3; i++) {
        int c = t + i * 256;
        float o = g[c] * (v[i] - m) * ri + be[c];
        if (outf) outf[(size_t)r * 768 + c] = o;
        if (outb) outb[ob + c] = f2bf(o);
    }
}

// ---------------------------------------------------------------------------
// CSR build: cnt (atomics) -> exclusive scan (offs, cur) -> bucket fill
__global__ void edge_count(const int* __restrict__ ei, int* __restrict__ cnt, int E)
{
    int e = blockIdx.x * blockDim.x + threadIdx.x;
    if (e < E) atomicAdd(&cnt[ei[E + e]], 1);
}

__global__ __launch_bounds__(1024) void scan_offsets(
    const int* __restrict__ cnt, int* __restrict__ offs, int* __restrict__ cur, int n)
{
    __shared__ int part[1024];
    int t = threadIdx.x;
    int per = (n + 1023) / 1024;
    int base = t * per;
    int local = 0;
    for (int i = 0; i < per; i++) {
        int idx = base + i;
        if (idx < n) local += cnt[idx];
    }
    part[t] = local;
    __syncthreads();
    for (int off = 1; off < 1024; off <<= 1) {
        int v = (t >= off) ? part[t - off] : 0;
        __syncthreads();
        part[t] += v;
        __syncthreads();
    }
    int prefix = (t == 0) ? 0 : part[t - 1];
    for (int i = 0; i < per; i++) {
        int idx = base + i;
        if (idx < n) {
            offs[idx] = prefix;
            cur[idx] = prefix;
            prefix += cnt[idx];
        }
    }
}

__global__ void fill_edges(const int* __restrict__ ei, int* __restrict__ cur,
                           int* __restrict__ elist, int E)
{
    int e = blockIdx.x * blockDim.x + threadIdx.x;
    if (e < E) {
        int d = ei[E + e];
        int pos = atomicAdd(&cur[d], 1);
        elist[pos] = ei[e];    // src
    }
}

// aggN[d] = mean over in-edges of nodes2[src]; writes Abig cols 768:1536 (bf16).
__global__ __launch_bounds__(256) void gather_mean(
    const int* __restrict__ offs, const int* __restrict__ cnt, const int* __restrict__ elist,
    u16* Abig, int Nn, int Mpad)
{
    int w = threadIdx.x >> 6, l = threadIdx.x & 63;
    int d = blockIdx.x * 4 + w;
    if (d >= Mpad) return;
    float acc[12];
#pragma unroll
    for (int j = 0; j < 12; j++) acc[j] = 0.f;
    float inv = 0.f;
    if (d < Nn) {
        int base = offs[d], c = cnt[d];
        for (int i = 0; i < c; i++) {
            int s = elist[base + i];
            const ushort4* p = (const ushort4*)(Abig + (size_t)s * 1536);
#pragma unroll
            for (int j4 = 0; j4 < 3; j4++) {
                ushort4 v = p[j4 * 64 + l];
                acc[j4 * 4 + 0] += bf2f(v.x);
                acc[j4 * 4 + 1] += bf2f(v.y);
                acc[j4 * 4 + 2] += bf2f(v.z);
                acc[j4 * 4 + 3] += bf2f(v.w);
            }
        }
        inv = 1.f / (float)max(c, 1);
    }
    ushort4* q = (ushort4*)(Abig + (size_t)d * 1536 + 768);
#pragma unroll
    for (int j4 = 0; j4 < 3; j4++) {
        ushort4 o;
        o.x = f2bf(acc[j4 * 4 + 0] * inv);
        o.y = f2bf(acc[j4 * 4 + 1] * inv);
        o.z = f2bf(acc[j4 * 4 + 2] * inv);
        o.w = f2bf(acc[j4 * 4 + 3] * inv);
        q[j4 * 64 + l] = o;
    }
}

// ---------------------------------------------------------------------------
// enc2_head: out2 readout + qkv + attn + o-proj + LN(g2a) -> x21 [256,64]
__global__ __launch_bounds__(256) void enc2_head(
    const int* __restrict__ opt, const int* __restrict__ offs, const int* __restrict__ cnt,
    const int* __restrict__ elist, const float* __restrict__ C2, const float* __restrict__ bg,
    const float* __restrict__ w_qkv2, const float* __restrict__ b_qkv2,
    const float* __restrict__ w_o2, const float* __restrict__ b_o2,
    const float* __restrict__ g2a, const float* __restrict__ bb2a,
    float* __restrict__ x21)
{
    __shared__ float X[4][64];
    __shared__ float QKV[4][192];
    __shared__ float T[4][64];
    int b = blockIdx.x;
    int w = threadIdx.x >> 6, l = threadIdx.x & 63;
    int row = b * 4 + w;

    {
        int d = opt[row];
        float acc = bg[l] + C2[(size_t)d * 128 + 64 + l];
        int base = offs[d], c = cnt[d];
        for (int i = 0; i < c; i++) {
            int s = elist[base + i];
            acc += C2[(size_t)s * 128 + l];
        }
        X[w][l] = acc;
    }
    __syncthreads();

#pragma unroll
    for (int j = 0; j < 3; j++) {
        int n = l + j * 64;
        const float* wr = w_qkv2 + (size_t)n * 64;
        float s = b_qkv2[n];
        for (int k = 0; k < 64; k++) s += X[w][k] * wr[k];
        QKV[w][n] = s;
    }
    __syncthreads();

    {
        float q = QKV[w][l];
        float p0 = q * QKV[0][64 + l], p1 = q * QKV[1][64 + l];
        float p2 = q * QKV[2][64 + l], p3 = q * QKV[3][64 + l];
#pragma unroll
        for (int off = 1; off < 32; off <<= 1) {
            p0 += __shfl_xor(p0, off, 64); p1 += __shfl_xor(p1, off, 64);
            p2 += __shfl_xor(p2, off, 64); p3 += __shfl_xor(p3, off, 64);
        }
        p0 *= 0.1767766953f; p1 *= 0.1767766953f; p2 *= 0.1767766953f; p3 *= 0.1767766953f;
        float mx = fmaxf(fmaxf(p0, p1), fmaxf(p2, p3));
        float e0 = __expf(p0 - mx), e1 = __expf(p1 - mx), e2 = __expf(p2 - mx), e3 = __expf(p3 - mx);
        float inv = 1.f / (e0 + e1 + e2 + e3);
        T[w][l] = (e0 * QKV[0][128 + l] + e1 * QKV[1][128 + l] +
                   e2 * QKV[2][128 + l] + e3 * QKV[3][128 + l]) * inv;
    }
    __syncthreads();

    {
        const float* wr = w_o2 + (size_t)l * 64;
        float s = b_o2[l];
        for (int k = 0; k < 64; k++) s += T[w][k] * wr[k];
        float xa = s + X[w][l];
        float sum = xa, sq = xa * xa;
#pragma unroll
        for (int off = 1; off < 64; off <<= 1) {
            sum += __shfl_xor(sum, off, 64);
            sq  += __shfl_xor(sq, off, 64);
        }
        float m = sum * (1.f / 64.f);
        float ri = rsqrtf(sq * (1.f / 64.f) - m * m + 1e-5f);
        x21[(size_t)row * 64 + l] = g2a[l] * (xa - m) * ri + bb2a[l];
    }
}

// ff1: Hf[r,n] = relu(x21[r,:]·wf1[n,:] + bf1[n]); one output per thread.
__global__ __launch_bounds__(256) void ff1_par(
    const float* __restrict__ x21, const float* __restrict__ wf1,
    const float* __restrict__ bf1, float* __restrict__ Hf)
{
    __shared__ float X[64];
    int b = blockIdx.x, t = threadIdx.x;
    int r = b >> 3, n = (b & 7) * 256 + t;
    if (t < 64) X[t] = x21[(size_t)r * 64 + t];
    __syncthreads();
    const float4* wr4 = (const float4*)(wf1 + (size_t)n * 64);
    float s = bf1[n];
#pragma unroll
    for (int k4 = 0; k4 < 16; k4++) {
        float4 wv = wr4[k4];
        const float* xp = X + k4 * 4;
        s += wv.x * xp[0] + wv.y * xp[1] + wv.z * xp[2] + wv.w * xp[3];
    }
    Hf[(size_t)r * 2048 + n] = fmaxf(s, 0.f);
}

// ff2 + residual + LN(g2b) + l1 + tanh + l2. One block per row, 4 waves.
__global__ __launch_bounds__(256) void ff2_tail(
    const float* __restrict__ Hf, const float* __restrict__ x21,
    const float* __restrict__ wf2, const float* __restrict__ bf2,
    const float* __restrict__ g2b, const float* __restrict__ bb2b,
    const float* __restrict__ w_l1, const float* __restrict__ b_l1,
    const float* __restrict__ w_l2, const float* __restrict__ b_l2,
    float* __restrict__ out)
{
    __shared__ float HL[2048];
    __shared__ float part[4][64];
    __shared__ float X2[64];
    int r = blockIdx.x, t = threadIdx.x;
    int w = t >> 6, l = t & 63;

    {
        const float4* src = (const float4*)(Hf + (size_t)r * 2048);
        float4* dst = (float4*)HL;
        dst[t] = src[t];
        dst[t + 256] = src[t + 256];
    }
    __syncthreads();

    {
        const float4* wr4 = (const float4*)(wf2 + (size_t)l * 2048 + w * 512);
        const float* hp = HL + w * 512;
        float s = 0.f;
#pragma unroll 16
        for (int k4 = 0; k4 < 128; k4++) {
            float4 wv = wr4[k4];
            const float* xp = hp + k4 * 4;
            s += wv.x * xp[0] + wv.y * xp[1] + wv.z * xp[2] + wv.w * xp[3];
        }
        part[w][l] = s;
    }
    __syncthreads();

    if (w == 0) {
        float xa = part[0][l] + part[1][l] + part[2][l] + part[3][l] + bf2[l]
                 + x21[(size_t)r * 64 + l];
        float sum = xa, sq = xa * xa;
#pragma unroll
        for (int off = 1; off < 64; off <<= 1) {
            sum += __shfl_xor(sum, off, 64);
            sq  += __shfl_xor(sq, off, 64);
        }
        float m = sum * (1.f / 64.f);
        float ri = rsqrtf(sq * (1.f / 64.f) - m * m + 1e-5f);
        X2[l] = g2b[l] * (xa - m) * ri + bb2b[l];
        __builtin_amdgcn_wave_barrier();
        const float* wr = w_l1 + (size_t)l * 64;
        float s = b_l1[l];
        for (int k = 0; k < 64; k++) s += X2[k] * wr[k];
        float tv = tanhf(s);
        float p = tv * w_l2[l];
#pragma unroll
        for (int off = 1; off < 64; off <<= 1) p += __shfl_xor(p, off, 64);
        if (l == 0) out[r] = p + b_l2[0];
    }
}

// ---------------------------------------------------------------------------
extern "C" void kernel_launch(void* const* d_in, const int* in_sizes, int n_in,
                              void* d_out, int out_size, void* d_ws, size_t ws_size,
                              hipStream_t stream)
{
    const float* nodes  = (const float*)d_in[0];
    const int*   ei     = (const int*)d_in[1];
    const int*   opt    = (const int*)d_in[2];
    const float* w_qkv1 = (const float*)d_in[3];
    const float* b_qkv1 = (const float*)d_in[4];
    const float* w_o1   = (const float*)d_in[5];
    const float* b_o1   = (const float*)d_in[6];
    const float* g1a    = (const float*)d_in[7];
    const float* bb1a   = (const float*)d_in[8];
    const float* w_ff1a = (const float*)d_in[9];
    const float* bf1a   = (const float*)d_in[10];
    const float* w_ff1b = (const float*)d_in[11];
    const float* bf1b   = (const float*)d_in[12];
    const float* g1b    = (const float*)d_in[13];
    const float* bb1b   = (const float*)d_in[14];
    // d_in[15..28]: wq..b6 — dead code (edge_type ≡ 0: softmax over singleton axis)
    const float* w_rel  = (const float*)d_in[29];
    const float* w_root = (const float*)d_in[30];
    const float* b_rgcn = (const float*)d_in[31];
    const float* wg_rel = (const float*)d_in[32];
    const float* wg_root= (const float*)d_in[33];
    const float* bg     = (const float*)d_in[34];
    const float* w_qkv2 = (const float*)d_in[35];
    const float* b_qkv2 = (const float*)d_in[36];
    const float* w_o2   = (const float*)d_in[37];
    const float* b_o2   = (const float*)d_in[38];
    const float* g2a    = (const float*)d_in[39];
    const float* bb2a   = (const float*)d_in[40];
    const float* w_ff2a = (const float*)d_in[41];
    const float* bf2a   = (const float*)d_in[42];
    const float* w_ff2b = (const float*)d_in[43];
    const float* bf2b   = (const float*)d_in[44];
    const float* g2b    = (const float*)d_in[45];
    const float* bb2b   = (const float*)d_in[46];
    const float* w_l1   = (const float*)d_in[47];
    const float* b_l1   = (const float*)d_in[48];
    const float* w_l2   = (const float*)d_in[49];
    const float* b_l2   = (const float*)d_in[50];

    const int H = 768, F = 2048;
    const int Nn = in_sizes[0] / H;            // 20000
    const int E  = in_sizes[1] / 2;            // 40000
    const int R  = in_sizes[2];                // 256 option rows
    const int Mpad = (Nn + 127) & ~127;        // 20096
    const int Bb = R / 4;                      // 64 batches

    char* ws = (char*)d_ws;
    size_t off = 0;
    auto alloc = [&](size_t b) -> char* {
        char* p = ws + off; off += (b + 255) & ~(size_t)255; return p;
    };
    // bf16 weights
    u16* wqkv1b  = (u16*)alloc((size_t)3 * H * H * 2);
    u16* wo1b    = (u16*)alloc((size_t)H * H * 2);
    u16* wff1ab  = (u16*)alloc((size_t)F * H * 2);
    u16* wff1bb  = (u16*)alloc((size_t)H * F * 2);
    u16* Wbraw   = (u16*)alloc((size_t)1536 * H * 2);     // [w_root ; w_rel0] row-major bf16
    u16* W2tb    = (u16*)alloc((size_t)128 * H * 2);      // [wg_rel^T ; wg_root^T]
    u16* WcT     = (u16*)alloc((size_t)128 * 1536 * 2);   // (Wb @ W2)^T  bf16
    float* bc    = (float*)alloc((size_t)128 * 4);        // b_rgcn @ W2
    // split-K partial buffer (reused sequentially; max = qkv 4x256x2304)
    float* Psk  = (float*)alloc((size_t)4 * 256 * 2304 * 4);
    // encoder1 activations
    float* x0   = (float*)alloc((size_t)R * H * 4);
    u16*  x0b   = (u16*)alloc((size_t)R * H * 2);
    u16*  atnob = (u16*)alloc((size_t)R * H * 2);
    float* x1   = (float*)alloc((size_t)R * H * 4);
    u16*  x1b   = (u16*)alloc((size_t)R * H * 2);
    u16*  ffhb  = (u16*)alloc((size_t)R * F * 2);
    // big buffers
    u16*  Abig  = (u16*)alloc((size_t)Mpad * 1536 * 2);   // [nodes2 | aggN] bf16
    float* C2   = (float*)alloc((size_t)Mpad * 128 * 4);
    // CSR
    int* cnt   = (int*)alloc((size_t)Nn * 4);
    int* offs  = (int*)alloc((size_t)Nn * 4);
    int* cur   = (int*)alloc((size_t)Nn * 4);
    int* elist = (int*)alloc((size_t)E * 4);
    // tail
    float* x21 = (float*)alloc((size_t)R * 64 * 4);
    float* Hf2 = (float*)alloc((size_t)R * F * 4);
    (void)ws_size; (void)n_in; (void)out_size;

    // ---- weight prep ----
    {
        CJobs6 cj;
        cj.j[0] = { w_qkv1, wqkv1b, (long)3 * H * H / 4 };
        cj.j[1] = { w_o1,   wo1b,   (long)H * H / 4 };
        cj.j[2] = { w_ff1a, wff1ab, (long)F * H / 4 };
        cj.j[3] = { w_ff1b, wff1bb, (long)H * F / 4 };
        cj.j[4] = { w_root, Wbraw,                    (long)H * H / 4 };
        cj.j[5] = { w_rel,  Wbraw + (size_t)H * H,    (long)H * H / 4 };   // w_rel[0] only
        conv6_bf16<<<dim3(432, 1, 6), 256, 0, stream>>>(cj);
        TJobs2 tj;
        tj.j[0] = { wg_rel,  W2tb,                    768, 64, 768 };
        tj.j[1] = { wg_root, W2tb + (size_t)64 * 768, 768, 64, 768 };
        transpose2_bf16<<<dim3(2, 24, 2), dim3(32, 8), 0, stream>>>(tj);
    }
    // WcT = (Wb@W2)^T via split-K (KS=4) + bf16 reduce
    gemm_bt_sk<<<dim3(12, 1, 4), 256, 0, stream>>>(W2tb, Wbraw, Psk, 128, 1536, 768, 192);
    sk_reduce_b<<<768, 256, 0, stream>>>(Psk, 4, (long)128 * 1536, 1536, nullptr, 0, WcT);
    bc_prep<<<1, 128, 0, stream>>>(b_rgcn, wg_rel, wg_root, bc);

    // ---- nodes2 into Abig cols 0:768 (before enc1: ln_reduce overwrites opt rows) ----
    conv_nodes_str<<<2048, 256, 0, stream>>>(nodes, Abig, Nn, Mpad);

    // ---- encoder layer 1 on option nodes (256 x 768), split-K GEMMs ----
    gather_x0<<<R, 256, 0, stream>>>(nodes, opt, x0, x0b, H);
    gemm_bt_sk<<<dim3(18, 2, 4), 256, 0, stream>>>(x0b, wqkv1b, Psk, R, 3 * H, H, 192);
    attn_fused<<<Bb * 2, 256, 0, stream>>>(Psk, 4, b_qkv1, atnob);
    gemm_bt_sk<<<dim3(6, 2, 4), 256, 0, stream>>>(atnob, wo1b, Psk, R, H, H, 192);
    ln_reduce768<<<R, 256, 0, stream>>>(Psk, 4, b_o1, x0, g1a, bb1a, x1, x1b, nullptr, 768);
    gemm_bt_sk<<<dim3(16, 2, 4), 256, 0, stream>>>(x1b, wff1ab, Psk, R, F, H, 192);
    sk_reduce_b<<<2048, 256, 0, stream>>>(Psk, 4, (long)R * F, F, bf1a, 1, ffhb);
    gemm_bt_sk<<<dim3(6, 2, 8), 256, 0, stream>>>(ffhb, wff1bb, Psk, R, H, F, 256);
    ln_reduce768<<<R, 256, 0, stream>>>(Psk, 8, bf1b, x1, g1b, bb1b, nullptr, Abig, opt, 1536);

    // ---- CSR build + mean-aggregate nodes2 into Abig cols 768:1536 ----
    hipMemsetAsync(cnt, 0, (size_t)Nn * 4, stream);
    edge_count<<<(E + 255) / 256, 256, 0, stream>>>(ei, cnt, E);
    scan_offsets<<<1, 1024, 0, stream>>>(cnt, offs, cur, Nn);
    fill_edges<<<(E + 255) / 256, 256, 0, stream>>>(ei, cur, elist, E);
    gather_mean<<<Mpad / 4, 256, 0, stream>>>(offs, cnt, elist, Abig, Nn, Mpad);

    // ---- fused RGCN+GraphConv projection: C2 = Abig @ Wc + bc ----
    gemm_bt<<<dim3(1, Mpad / 128), 256, 0, stream>>>(Abig, WcT, C2, nullptr, bc, Mpad, 128, 1536, 0);

    // ---- tail ----
    enc2_head<<<Bb, 256, 0, stream>>>(opt, offs, cnt, elist, C2, bg,
                                      w_qkv2, b_qkv2, w_o2, b_o2, g2a, bb2a, x21);
    ff1_par<<<R * 8, 256, 0, stream>>>(x21, w_ff2a, bf2a, Hf2);
    ff2_tail<<<R, 256, 0, stream>>>(Hf2, x21, w_ff2b, bf2b, g2b, bb2b,
                                    w_l1, b_l1, w_l2, b_l2, (float*)d_out);
}